// Round 10
// baseline (136.487 us; speedup 1.0000x reference)
//
#include <hip/hip_runtime.h>
#include <stdint.h>

#define N_EMBD 1024
#define N_HEADv 16
#define HEADv 64
#define Bv 2
#define Tv 2048
#define BT (Bv*Tv)      // 4096
#define C3 (3*N_EMBD)   // 3072

typedef __attribute__((ext_vector_type(8))) short bf16x8;
typedef __attribute__((ext_vector_type(4))) float f32x4;

typedef __attribute__((address_space(3))) uint32_t lds_u32;
typedef const __attribute__((address_space(1))) uint32_t glb_u32;

__device__ __forceinline__ void gload_lds16(const void* g, void* l){
  __builtin_amdgcn_global_load_lds((glb_u32*)g, (lds_u32*)l, 16, 0, 0);
}

__device__ __forceinline__ unsigned short f2bf(float f){
  union { float f; uint32_t u; } v; v.f = f;
  uint32_t u = v.u;
  uint32_t r = u + 0x7FFFu + ((u>>16)&1u);
  return (unsigned short)(r>>16);
}
__device__ __forceinline__ uint32_t f2bf_fast(float f){
  union { float f; uint32_t u; } v; v.f = f;
  return (v.u + 0x8000u) >> 16;
}
__device__ __forceinline__ float bf2f(unsigned short s){
  union { uint32_t u; float f; } v; v.u = ((uint32_t)s)<<16; return v.f;
}

// ---------------- fp32 -> bf16 elementwise ----------------
__global__ void k_cvt_bf16(const float* __restrict__ in, unsigned short* __restrict__ out, long n){
  long i = ((long)blockIdx.x*blockDim.x + threadIdx.x)*8;
  if(i >= n) return;
  float4 a = *reinterpret_cast<const float4*>(in+i);
  float4 b = *reinterpret_cast<const float4*>(in+i+4);
  union { int4 v; unsigned short s[8]; } o;
  o.s[0]=f2bf(a.x); o.s[1]=f2bf(a.y); o.s[2]=f2bf(a.z); o.s[3]=f2bf(a.w);
  o.s[4]=f2bf(b.x); o.s[5]=f2bf(b.y); o.s[6]=f2bf(b.z); o.s[7]=f2bf(b.w);
  *reinterpret_cast<int4*>(out+i) = o.v;
}

// ---------------- fp32 [K][N] -> bf16 [N][K] transpose ----------------
__global__ void k_transpose_bf16(const float* __restrict__ in, unsigned short* __restrict__ out, int K, int N){
  __shared__ float tile[64][65];
  int n0 = blockIdx.x*64, k0 = blockIdx.y*64;
  int t = threadIdx.x;
  #pragma unroll
  for(int p=0;p<4;p++){
    int row = (t>>4) + p*16;
    int col4 = (t&15)*4;
    float4 v = *reinterpret_cast<const float4*>(&in[(size_t)(k0+row)*N + n0 + col4]);
    tile[row][col4+0]=v.x; tile[row][col4+1]=v.y; tile[row][col4+2]=v.z; tile[row][col4+3]=v.w;
  }
  __syncthreads();
  #pragma unroll
  for(int p=0;p<4;p++){
    int nrow = (t>>4) + p*16;
    int kc = (t&15)*4;
    ushort4 o;
    o.x = f2bf(tile[kc+0][nrow]);
    o.y = f2bf(tile[kc+1][nrow]);
    o.z = f2bf(tile[kc+2][nrow]);
    o.w = f2bf(tile[kc+3][nrow]);
    *reinterpret_cast<ushort4*>(&out[(size_t)(n0+nrow)*K + k0 + kc]) = o;
  }
}

// ---------------- bf16 MFMA GEMM: C = A[M][K] @ Bt[N][K]^T + bias ----------------
// BK=32 double-buffered (32 KB LDS -> 4-5 blocks/CU TLP) + issue-next-first
// depth-1 prefetch. 1D grid with XCD-chunked swizzle (m fastest within XCD:
// each XCD keeps its B-panels resident in private L2).
// 64B LDS rows, 2-bit XOR swizzle slot^=(row&3); gload_lds linear dest +
// pre-swizzled global source (rule 21). Conflict-free b128 reads.
// MODE 0: scatter Q*SC,K -> [b,h,t,d]; V -> [b,h,d,t] (fused transpose).
// MODE 1: fp32 out [M][N], swapped-operand D^T epilogue -> float4 stores.
template<int MODE>
__global__ __launch_bounds__(256) void k_gemm(
    const unsigned short* __restrict__ A,
    const unsigned short* __restrict__ Bt,
    const float* __restrict__ bias,
    void* __restrict__ Cout,
    int M, int N, int K)
{
  const int BK=32;
  const int TSZ=128*BK;                    // 4096 elems = 8 KB per buffer
  __shared__ unsigned short As[2*TSZ];     // 16 KB
  __shared__ unsigned short Bs[2*TSZ];     // 16 KB
  // XCD swizzle: contiguous chunk of wgids per XCD, m fastest (M/128 == 32)
  int bpx = gridDim.x >> 3;
  int wgid = (blockIdx.x & 7)*bpx + (blockIdx.x >> 3);
  int m0 = (wgid & 31)*128, n0 = (wgid >> 5)*128;
  int t = threadIdx.x, lane = t&63, wid = t>>6;
  int wm = (wid>>1)*64, wn = (wid&1)*64;
  int g = lane>>4, r16 = lane&15;
  // staging: lane -> row wid*16+(lane>>2) (+64), slot lane&3; source col
  // pre-swizzled so read-side XOR decodes it.
  int rl  = lane>>2;                       // 0..15
  int scol = ((lane&3) ^ (rl&3))*8;        // inverse-swizzled col (bf16 elems)
  int rk = r16 & 3;                        // read-side swizzle key
  f32x4 acc[4][4] = {};

  // prologue: stage tile 0 into buffer 0
  #pragma unroll
  for(int c=0;c<2;c++){
    int rb = wid*16 + c*64;
    gload_lds16(&A [(size_t)(m0+rb+rl)*K + scol], &As[rb*BK]);
    gload_lds16(&Bt[(size_t)(n0+rb+rl)*K + scol], &Bs[rb*BK]);
  }
  __syncthreads();

  const int NIT = K/BK;
  for(int it=0; it<NIT; ++it){
    int cur = it & 1;
    // issue next tile's loads FIRST -> in flight during compute
    if(it+1 < NIT){
      int k0 = (it+1)*BK;
      int nxt = (cur^1)*TSZ;
      #pragma unroll
      for(int c=0;c<2;c++){
        int rb = wid*16 + c*64;
        gload_lds16(&A [(size_t)(m0+rb+rl)*K + k0 + scol], &As[nxt + rb*BK]);
        gload_lds16(&Bt[(size_t)(n0+rb+rl)*K + k0 + scol], &Bs[nxt + rb*BK]);
      }
    }
    const unsigned short* Ab = &As[cur*TSZ];
    const unsigned short* Bb = &Bs[cur*TSZ];
    bf16x8 af[4], bfr[4];
    #pragma unroll
    for(int mi=0;mi<4;mi++)
      af[mi]  = *reinterpret_cast<const bf16x8*>(&Ab[(wm+mi*16+r16)*BK + ((g^rk)*8)]);
    #pragma unroll
    for(int ni=0;ni<4;ni++)
      bfr[ni] = *reinterpret_cast<const bf16x8*>(&Bb[(wn+ni*16+r16)*BK + ((g^rk)*8)]);
    __builtin_amdgcn_s_setprio(1);
    #pragma unroll
    for(int mi=0;mi<4;mi++)
      #pragma unroll
      for(int ni=0;ni<4;ni++){
        if(MODE==0)
          acc[mi][ni] = __builtin_amdgcn_mfma_f32_16x16x32_bf16(af[mi], bfr[ni], acc[mi][ni], 0,0,0);
        else
          acc[mi][ni] = __builtin_amdgcn_mfma_f32_16x16x32_bf16(bfr[ni], af[mi], acc[mi][ni], 0,0,0);
      }
    __builtin_amdgcn_s_setprio(0);
    __syncthreads();
  }

  if(MODE==0){
    int which = (n0+wn)>>10;
    int h = ((n0+wn)&1023)>>6;
    int bb = m0>>11;
    int tt0 = (m0&2047) + wm;
    unsigned short* base = (unsigned short*)Cout;
    if(which < 2){
      // Q pre-scaled by (1/8)*log2(e) so attn uses sacc directly in exp2 domain
      float scale = (which==0) ? 0.18033688f : 1.0f;   // wave-uniform
      unsigned short* dst = base + (size_t)which*BT*N_EMBD
                          + (((size_t)bb*N_HEADv + h)*Tv + tt0)*HEADv;
      #pragma unroll
      for(int ni=0;ni<4;ni++){
        float bv = bias[n0+wn+ni*16+r16];
        int d = ni*16 + r16;
        #pragma unroll
        for(int mi=0;mi<4;mi++)
          #pragma unroll
          for(int reg=0;reg<4;reg++){
            int tt = mi*16 + g*4 + reg;
            dst[(size_t)tt*HEADv + d] = f2bf((acc[mi][ni][reg] + bv)*scale);
          }
      }
    } else {
      unsigned short* dst = base + 2ll*BT*N_EMBD
                          + (((size_t)bb*N_HEADv + h)*HEADv)*Tv + tt0;
      #pragma unroll
      for(int ni=0;ni<4;ni++){
        float bv = bias[n0+wn+ni*16+r16];
        int d = ni*16 + r16;
        #pragma unroll
        for(int mi=0;mi<4;mi++)
          #pragma unroll
          for(int reg=0;reg<4;reg++){
            int tt = mi*16 + g*4 + reg;
            dst[(size_t)d*Tv + tt] = f2bf(acc[mi][ni][reg] + bv);
          }
      }
    }
  } else {
    float* out = (float*)Cout;
    #pragma unroll
    for(int mi=0;mi<4;mi++){
      int m = m0+wm+mi*16+r16;
      #pragma unroll
      for(int ni=0;ni<4;ni++){
        int n = n0+wn+ni*16+g*4;
        float4 b4 = *reinterpret_cast<const float4*>(&bias[n]);
        float4 o4;
        o4.x = acc[mi][ni][0] + b4.x;
        o4.y = acc[mi][ni][1] + b4.y;
        o4.z = acc[mi][ni][2] + b4.z;
        o4.w = acc[mi][ni][3] + b4.w;
        *reinterpret_cast<float4*>(&out[(size_t)m*N + n]) = o4;
      }
    }
  }
}

// ---------------- flash attention (causal), split-K chunks ----------------
// Q pre-scaled by (1/8)log2e -> sacc is directly in exp2 domain.
// Speculative exp2 (no max-tree dep) + rare repair branch; l via ones-MFMA.
__global__ __launch_bounds__(256) void k_attn(
    const unsigned short* __restrict__ QKV,
    unsigned short* __restrict__ O,
    unsigned short* __restrict__ partO,
    float2* __restrict__ stats)
{
  __shared__ unsigned short Ks[2][64][64];   // [buf][key][d], swizzled cols
  __shared__ unsigned short Vs[2][64][64];   // [buf][d][key]
  __shared__ unsigned short Ps[4][16][64];   // [wave][q][key]
  int blk = blockIdx.x;
  int bh = blk & 31;
  int j  = blk >> 5;
  int qt, kt0, ktN; bool single;
  if(j < 16)      { qt = 16+j;  kt0 = 0;  ktN = 16;    single = false; }
  else if(j < 32) { qt = 47-j;  kt0 = 16; ktN = qt+1;  single = false; }
  else            { qt = 47-j;  kt0 = 0;  ktN = qt+1;  single = true;  }

  int t = threadIdx.x, lane=t&63, wid=t>>6;
  int g = lane>>4, r16 = lane&15;
  const unsigned short* Qp  = QKV + (size_t)bh*Tv*HEADv;
  const unsigned short* Kp  = QKV + (size_t)BT*N_EMBD + (size_t)bh*Tv*HEADv;
  const unsigned short* Vtp = QKV + 2ll*BT*N_EMBD + (size_t)bh*HEADv*Tv;
  int q0 = qt*64 + wid*16;

  bf16x8 aq[2];   // B-operand: col = q = r16
  #pragma unroll
  for(int kb=0;kb<2;kb++)
    aq[kb] = *reinterpret_cast<const bf16x8*>(&Qp[(size_t)(q0+r16)*HEADv + kb*32 + g*8]);

  const short ONE = (short)0x3F80;           // bf16 1.0
  const bf16x8 ones8 = {ONE,ONE,ONE,ONE,ONE,ONE,ONE,ONE};

  f32x4 oacc[4] = {};
  f32x4 lacc = {};            // l via ones-MFMA (element 0 used)
  float m2 = 6.0f;            // warm init (log2 domain)

  // staging: thread covers rows t>>3 and t>>3+32, 16B slot t&7
  int r0 = t>>3, c0 = (t&7)*8;
  int r1 = r0 + 32;
  int sw0 = c0 ^ ((r0&7)<<3);
  int sw1 = c0 ^ ((r1&7)<<3);
  int rsw = (r16&7)<<3;

  // prologue: tile kt0 -> regs -> buf0 ; issue tile kt0+1 loads
  int4 kc0, kc1, vc0, vc1;
  kc0 = *reinterpret_cast<const int4*>(&Kp [(size_t)(kt0*64+r0)*HEADv + c0]);
  kc1 = *reinterpret_cast<const int4*>(&Kp [(size_t)(kt0*64+r1)*HEADv + c0]);
  vc0 = *reinterpret_cast<const int4*>(&Vtp[(size_t)r0*Tv + kt0*64 + c0]);
  vc1 = *reinterpret_cast<const int4*>(&Vtp[(size_t)r1*Tv + kt0*64 + c0]);
  *reinterpret_cast<int4*>(&Ks[0][r0][sw0]) = kc0;
  *reinterpret_cast<int4*>(&Ks[0][r1][sw1]) = kc1;
  *reinterpret_cast<int4*>(&Vs[0][r0][sw0]) = vc0;
  *reinterpret_cast<int4*>(&Vs[0][r1][sw1]) = vc1;
  if(ktN - kt0 > 1){
    kc0 = *reinterpret_cast<const int4*>(&Kp [(size_t)((kt0+1)*64+r0)*HEADv + c0]);
    kc1 = *reinterpret_cast<const int4*>(&Kp [(size_t)((kt0+1)*64+r1)*HEADv + c0]);
    vc0 = *reinterpret_cast<const int4*>(&Vtp[(size_t)r0*Tv + (kt0+1)*64 + c0]);
    vc1 = *reinterpret_cast<const int4*>(&Vtp[(size_t)r1*Tv + (kt0+1)*64 + c0]);
  }
  __syncthreads();

  for(int kt=kt0; kt<ktN; ++kt){
    int cur = kt & 1;
    if(kt+1 < ktN){
      *reinterpret_cast<int4*>(&Ks[cur^1][r0][sw0]) = kc0;
      *reinterpret_cast<int4*>(&Ks[cur^1][r1][sw1]) = kc1;
      *reinterpret_cast<int4*>(&Vs[cur^1][r0][sw0]) = vc0;
      *reinterpret_cast<int4*>(&Vs[cur^1][r1][sw1]) = vc1;
      if(kt+2 < ktN){
        kc0 = *reinterpret_cast<const int4*>(&Kp [(size_t)((kt+2)*64+r0)*HEADv + c0]);
        kc1 = *reinterpret_cast<const int4*>(&Kp [(size_t)((kt+2)*64+r1)*HEADv + c0]);
        vc0 = *reinterpret_cast<const int4*>(&Vtp[(size_t)r0*Tv + (kt+2)*64 + c0]);
        vc1 = *reinterpret_cast<const int4*>(&Vtp[(size_t)r1*Tv + (kt+2)*64 + c0]);
      }
    }

    // S^T (already exp2-domain): sacc[nb][reg] = S[q=q0+r16][key = kt*64+nb*16+g*4+reg]
    f32x4 sacc[4];
    __builtin_amdgcn_s_setprio(1);
    #pragma unroll
    for(int nb=0;nb<4;nb++){
      sacc[nb] = (f32x4){0.f,0.f,0.f,0.f};
      #pragma unroll
      for(int kb=0;kb<2;kb++){
        bf16x8 bk = *reinterpret_cast<const bf16x8*>(&Ks[cur][nb*16+r16][(kb*32+g*8) ^ rsw]);
        sacc[nb] = __builtin_amdgcn_mfma_f32_16x16x32_bf16(bk, aq[kb], sacc[nb],0,0,0);
      }
    }
    __builtin_amdgcn_s_setprio(0);

    bool diag = (kt == qt);
    float sv[4][4], pv[4][4];
    #pragma unroll
    for(int nb=0;nb<4;nb++)
      #pragma unroll
      for(int reg=0;reg<4;reg++){
        float s = sacc[nb][reg];
        if(diag){
          int keyin = nb*16 + g*4 + reg;
          if(keyin > wid*16 + r16) s = -1e30f;
        }
        sv[nb][reg] = s;
      }
    // speculative exp2: no dependency on the row-max
    #pragma unroll
    for(int nb=0;nb<4;nb++)
      #pragma unroll
      for(int reg=0;reg<4;reg++)
        pv[nb][reg] = __builtin_amdgcn_exp2f(sv[nb][reg] - m2);

    // parallel path: row max -> rare repair branch
    float mxnb[4];
    #pragma unroll
    for(int nb=0;nb<4;nb++)
      mxnb[nb] = fmaxf(fmaxf(sv[nb][0],sv[nb][1]), fmaxf(sv[nb][2],sv[nb][3]));
    float mx = fmaxf(fmaxf(mxnb[0],mxnb[1]), fmaxf(mxnb[2],mxnb[3]));
    mx = fmaxf(mx, __shfl_xor(mx, 16, 64));
    mx = fmaxf(mx, __shfl_xor(mx, 32, 64));

    if(!__all(mx - m2 <= 11.5f)){
      float mn = fmaxf(m2, mx);
      float alpha = __builtin_amdgcn_exp2f(m2 - mn);
      lacc[0]*=alpha; lacc[1]*=alpha; lacc[2]*=alpha; lacc[3]*=alpha;
      #pragma unroll
      for(int nb=0;nb<4;nb++)
        #pragma unroll
        for(int reg=0;reg<4;reg++) oacc[nb][reg] *= alpha;
      m2 = mn;
      #pragma unroll
      for(int nb=0;nb<4;nb++)
        #pragma unroll
        for(int reg=0;reg<4;reg++)
          pv[nb][reg] = __builtin_amdgcn_exp2f(sv[nb][reg] - m2);
    }

    #pragma unroll
    for(int nb=0;nb<4;nb++){
      union { uint32_t u[2]; int2 v; } w;
      w.u[0] = f2bf_fast(pv[nb][0]) | (f2bf_fast(pv[nb][1])<<16);
      w.u[1] = f2bf_fast(pv[nb][2]) | (f2bf_fast(pv[nb][3])<<16);
      *reinterpret_cast<int2*>(&Ps[wid][r16][(nb*16+g*4) ^ rsw]) = w.v;
    }

    // PV (+ l via ones-MFMA): contraction over keys handles cross-lane sum
    __builtin_amdgcn_s_setprio(1);
    #pragma unroll
    for(int kb=0;kb<2;kb++){
      bf16x8 ap = *reinterpret_cast<const bf16x8*>(&Ps[wid][r16][(kb*32+g*8) ^ rsw]);
      lacc = __builtin_amdgcn_mfma_f32_16x16x32_bf16(ones8, ap, lacc,0,0,0);
      #pragma unroll
      for(int nb=0;nb<4;nb++){
        bf16x8 bv = *reinterpret_cast<const bf16x8*>(&Vs[cur][nb*16+r16][(kb*32+g*8) ^ rsw]);
        oacc[nb] = __builtin_amdgcn_mfma_f32_16x16x32_bf16(bv, ap, oacc[nb],0,0,0);
      }
    }
    __builtin_amdgcn_s_setprio(0);
    __syncthreads();
  }

  float l = lacc[0];
  float rinv = 1.0f / l;
  if(single){
    int b = bh >> 4, h = bh & 15;
    size_t row = (size_t)b*Tv + q0 + r16;
    #pragma unroll
    for(int nb=0;nb<4;nb++){
      ushort4 o;
      o.x = f2bf(oacc[nb][0]*rinv);
      o.y = f2bf(oacc[nb][1]*rinv);
      o.z = f2bf(oacc[nb][2]*rinv);
      o.w = f2bf(oacc[nb][3]*rinv);
      *reinterpret_cast<ushort4*>(&O[row*N_EMBD + h*HEADv + nb*16 + g*4]) = o;
    }
  } else {
    int part = j*32 + bh;
    unsigned short* po = partO + (size_t)part*4096;
    int qloc = wid*16 + r16;
    #pragma unroll
    for(int nb=0;nb<4;nb++){
      ushort4 o;
      o.x = f2bf(oacc[nb][0]*rinv);
      o.y = f2bf(oacc[nb][1]*rinv);
      o.z = f2bf(oacc[nb][2]*rinv);
      o.w = f2bf(oacc[nb][3]*rinv);
      *reinterpret_cast<ushort4*>(&po[qloc*64 + nb*16 + g*4]) = o;
    }
    if(g==0) stats[part*64 + qloc] = make_float2(m2, l);
  }
}

// ---------------- merge two partials per (bh, qt>=16) ----------------
__global__ __launch_bounds__(256) void k_merge(
    const unsigned short* __restrict__ partO,
    const float2* __restrict__ stats,
    unsigned short* __restrict__ O)
{
  int blk = blockIdx.x;            // 512
  int bh = blk & 31, qt = 16 + (blk >> 5);
  int p0 = (qt-16)*32 + bh;
  int p1 = (47-qt)*32 + bh;
  int t = threadIdx.x;
  int q = t >> 2, d0 = (t&3)*16;
  float2 s0 = stats[p0*64 + q];
  float2 s1 = stats[p1*64 + q];
  float m = fmaxf(s0.x, s1.x);
  float w0 = s0.y * __builtin_amdgcn_exp2f(s0.x - m);
  float w1 = s1.y * __builtin_amdgcn_exp2f(s1.x - m);
  float rinv = 1.f/(w0+w1);
  w0 *= rinv; w1 *= rinv;
  const unsigned short* a = partO + (size_t)p0*4096 + q*64 + d0;
  const unsigned short* b = partO + (size_t)p1*4096 + q*64 + d0;
  int bb = bh >> 4, h = bh & 15;
  unsigned short* o = O + ((size_t)bb*Tv + qt*64 + q)*N_EMBD + h*HEADv + d0;
  #pragma unroll
  for(int half=0; half<2; ++half){
    union { int4 v; unsigned short s[8]; } ua, ub, uo;
    ua.v = *reinterpret_cast<const int4*>(a + half*8);
    ub.v = *reinterpret_cast<const int4*>(b + half*8);
    #pragma unroll
    for(int e=0;e<8;e++)
      uo.s[e] = f2bf(bf2f(ua.s[e])*w0 + bf2f(ub.s[e])*w1);
    *reinterpret_cast<int4*>(o + half*8) = uo.v;
  }
}

extern "C" void kernel_launch(void* const* d_in, const int* in_sizes, int n_in,
                              void* d_out, int out_size, void* d_ws, size_t ws_size,
                              hipStream_t stream){
  const float* x      = (const float*)d_in[0];
  const float* w_attn = (const float*)d_in[1];
  const float* b_attn = (const float*)d_in[2];
  const float* w_proj = (const float*)d_in[3];
  const float* b_proj = (const float*)d_in[4];
  char* ws = (char*)d_ws;
  unsigned short* xb  = (unsigned short*)ws;                        // 8 MB  (dead after gemm0 -> partO)
  unsigned short* qkv = (unsigned short*)(ws + 8ll*1024*1024);      // 24 MB (V third stored transposed)
  unsigned short* ob  = (unsigned short*)(ws + 32ll*1024*1024);     // 8 MB
  unsigned short* wat = (unsigned short*)(ws + 40ll*1024*1024);     // 6 MB  (dead after gemm0 -> stats)
  unsigned short* wpt = (unsigned short*)(ws + 46ll*1024*1024);     // 2 MB
  unsigned short* partO = xb;                                       // 1024 * 8KB = 8 MB
  float2*        stats  = (float2*)wat;                             // 1024 * 512B = 512 KB

  k_cvt_bf16<<<2048,256,0,stream>>>(x, xb, (long)BT*N_EMBD);
  k_transpose_bf16<<<dim3(C3/64, N_EMBD/64),256,0,stream>>>(w_attn, wat, N_EMBD, C3);
  k_transpose_bf16<<<dim3(N_EMBD/64, N_EMBD/64),256,0,stream>>>(w_proj, wpt, N_EMBD, N_EMBD);
  k_gemm<0><<<dim3((C3/128)*(BT/128)),256,0,stream>>>(xb, wat, b_attn, (void*)qkv, BT, C3, N_EMBD);
  k_attn<<<dim3(48*32),256,0,stream>>>(qkv, ob, partO, stats);
  k_merge<<<dim3(512),256,0,stream>>>(partO, stats, ob);
  k_gemm<1><<<dim3((N_EMBD/128)*(BT/128)),256,0,stream>>>(ob, wpt, b_proj, d_out, BT, N_EMBD, N_EMBD);
}

// Round 12
// 117.361 us; speedup vs baseline: 1.1630x; 1.1630x over previous
//
#include <hip/hip_runtime.h>
#include <stdint.h>

#define N_EMBD 1024
#define N_HEADv 16
#define HEADv 64
#define Bv 2
#define Tv 2048
#define BT (Bv*Tv)      // 4096
#define C3 (3*N_EMBD)   // 3072

typedef __attribute__((ext_vector_type(8))) short bf16x8;
typedef __attribute__((ext_vector_type(4))) float f32x4;

typedef __attribute__((address_space(3))) uint32_t lds_u32;
typedef const __attribute__((address_space(1))) uint32_t glb_u32;

__device__ __forceinline__ void gload_lds16(const void* g, void* l){
  __builtin_amdgcn_global_load_lds((glb_u32*)g, (lds_u32*)l, 16, 0, 0);
}

__device__ __forceinline__ unsigned short f2bf(float f){
  union { float f; uint32_t u; } v; v.f = f;
  uint32_t u = v.u;
  uint32_t r = u + 0x7FFFu + ((u>>16)&1u);
  return (unsigned short)(r>>16);
}
__device__ __forceinline__ uint32_t f2bf_fast(float f){
  union { float f; uint32_t u; } v; v.f = f;
  return (v.u + 0x8000u) >> 16;
}
__device__ __forceinline__ float bf2f(unsigned short s){
  union { uint32_t u; float f; } v; v.u = ((uint32_t)s)<<16; return v.f;
}

// ---------------- fused prep: x->bf16 cvt + both weight transposes ----------------
// blk <2048: cvt chunk; <2816: w_attn [1024][3072] -> wat [3072][1024];
// else: w_proj [1024][1024] -> wpt [1024][1024]. Branch uniform per block.
__global__ __launch_bounds__(256) void k_prep(
    const float* __restrict__ x, unsigned short* __restrict__ xb,
    const float* __restrict__ w_attn, unsigned short* __restrict__ wat,
    const float* __restrict__ w_proj, unsigned short* __restrict__ wpt)
{
  __shared__ float tile[64][65];
  int blk = blockIdx.x;
  int t = threadIdx.x;
  if(blk < 2048){
    long i = ((long)blk*256 + t)*8;
    float4 a = *reinterpret_cast<const float4*>(x+i);
    float4 b = *reinterpret_cast<const float4*>(x+i+4);
    union { int4 v; unsigned short s[8]; } o;
    o.s[0]=f2bf(a.x); o.s[1]=f2bf(a.y); o.s[2]=f2bf(a.z); o.s[3]=f2bf(a.w);
    o.s[4]=f2bf(b.x); o.s[5]=f2bf(b.y); o.s[6]=f2bf(b.z); o.s[7]=f2bf(b.w);
    *reinterpret_cast<int4*>(xb+i) = o.v;
  } else {
    const float* in; unsigned short* out; int K, N, n0, k0;
    if(blk < 2816){
      int b = blk - 2048;
      in = w_attn; out = wat; K = N_EMBD; N = C3;
      n0 = (b % 48)*64; k0 = (b / 48)*64;
    } else {
      int b = blk - 2816;
      in = w_proj; out = wpt; K = N_EMBD; N = N_EMBD;
      n0 = (b % 16)*64; k0 = (b / 16)*64;
    }
    #pragma unroll
    for(int p=0;p<4;p++){
      int row = (t>>4) + p*16;
      int col4 = (t&15)*4;
      float4 v = *reinterpret_cast<const float4*>(&in[(size_t)(k0+row)*N + n0 + col4]);
      tile[row][col4+0]=v.x; tile[row][col4+1]=v.y; tile[row][col4+2]=v.z; tile[row][col4+3]=v.w;
    }
    __syncthreads();
    #pragma unroll
    for(int p=0;p<4;p++){
      int nrow = (t>>4) + p*16;
      int kc = (t&15)*4;
      ushort4 o;
      o.x = f2bf(tile[kc+0][nrow]);
      o.y = f2bf(tile[kc+1][nrow]);
      o.z = f2bf(tile[kc+2][nrow]);
      o.w = f2bf(tile[kc+3][nrow]);
      *reinterpret_cast<ushort4*>(&out[(size_t)(n0+nrow)*K + k0 + kc]) = o;
    }
  }
}

// ---------------- bf16 MFMA GEMM: C = A[M][K] @ Bt[N][K]^T + bias ----------------
// T3-minimum 2-phase: double-buffered LDS, gload_lds for tile t+1 issued at the
// START of iter t (latency hides under ds_read+MFMA), ONE barrier per iter.
// MODE 0: scatter Q*SC,K -> [b,h,t,d]; V -> [b,h,d,t] (fused transpose).
// MODE 1: fp32 out [M][N], swapped-operand D^T epilogue -> float4 stores.
template<int MODE>
__global__ __launch_bounds__(256) void k_gemm(
    const unsigned short* __restrict__ A,
    const unsigned short* __restrict__ Bt,
    const float* __restrict__ bias,
    void* __restrict__ Cout,
    int M, int N, int K)
{
  const int BK=64;
  const int TSZ=128*BK;                    // elems per buffer
  __shared__ unsigned short As[2*TSZ];     // 32 KB
  __shared__ unsigned short Bs[2*TSZ];     // 32 KB
  int m0 = blockIdx.y*128, n0 = blockIdx.x*128;
  int t = threadIdx.x, lane = t&63, wid = t>>6;
  int wm = (wid>>1)*64, wn = (wid&1)*64;
  int g = lane>>4, r16 = lane&15;
  int rl  = lane>>3;                 // 0..7 = row&7
  int cle = (((lane&7) ^ rl) * 8);   // inverse-swizzled col (bf16 elems)
  int rsw = r16 & 7;                 // read-side row swizzle key
  f32x4 acc[4][4] = {};

  // prologue: stage tile 0 into buffer 0
  #pragma unroll
  for(int c=0;c<4;c++){
    int rb = wid*32 + c*8;
    gload_lds16(&A [(size_t)(m0+rb+rl)*K + cle], &As[rb*BK]);
    gload_lds16(&Bt[(size_t)(n0+rb+rl)*K + cle], &Bs[rb*BK]);
  }
  __syncthreads();

  const int NIT = K/BK;
  for(int it=0; it<NIT; ++it){
    int cur = it & 1;
    // issue next tile's loads FIRST -> in flight during compute (T3/T14)
    if(it+1 < NIT){
      int k0 = (it+1)*BK;
      int nxt = (cur^1)*TSZ;
      #pragma unroll
      for(int c=0;c<4;c++){
        int rb = wid*32 + c*8;
        gload_lds16(&A [(size_t)(m0+rb+rl)*K + k0 + cle], &As[nxt + rb*BK]);
        gload_lds16(&Bt[(size_t)(n0+rb+rl)*K + k0 + cle], &Bs[nxt + rb*BK]);
      }
    }
    const unsigned short* Ab = &As[cur*TSZ];
    const unsigned short* Bb = &Bs[cur*TSZ];
    bf16x8 af[2][4], bfr[2][4];
    #pragma unroll
    for(int ks=0;ks<2;ks++){
      #pragma unroll
      for(int mi=0;mi<4;mi++)
        af[ks][mi]  = *reinterpret_cast<const bf16x8*>(&Ab[(wm+mi*16+r16)*BK + (((ks*4+g)^rsw)*8)]);
      #pragma unroll
      for(int ni=0;ni<4;ni++)
        bfr[ks][ni] = *reinterpret_cast<const bf16x8*>(&Bb[(wn+ni*16+r16)*BK + (((ks*4+g)^rsw)*8)]);
    }
    __builtin_amdgcn_s_setprio(1);
    #pragma unroll
    for(int ks=0;ks<2;ks++)
      #pragma unroll
      for(int mi=0;mi<4;mi++)
        #pragma unroll
        for(int ni=0;ni<4;ni++){
          if(MODE==0)
            acc[mi][ni] = __builtin_amdgcn_mfma_f32_16x16x32_bf16(af[ks][mi], bfr[ks][ni], acc[mi][ni], 0,0,0);
          else
            acc[mi][ni] = __builtin_amdgcn_mfma_f32_16x16x32_bf16(bfr[ks][ni], af[ks][mi], acc[mi][ni], 0,0,0);
        }
    __builtin_amdgcn_s_setprio(0);
    __syncthreads();   // drains next-tile gloads (had full compute phase in flight)
  }

  if(MODE==0){
    int which = (n0+wn)>>10;
    int h = ((n0+wn)&1023)>>6;
    int bb = m0>>11;
    int tt0 = (m0&2047) + wm;
    unsigned short* base = (unsigned short*)Cout;
    if(which < 2){
      // Q pre-scaled by (1/8)*log2(e) so attn uses sacc directly in exp2 domain
      float scale = (which==0) ? 0.18033688f : 1.0f;   // wave-uniform
      unsigned short* dst = base + (size_t)which*BT*N_EMBD
                          + (((size_t)bb*N_HEADv + h)*Tv + tt0)*HEADv;
      #pragma unroll
      for(int ni=0;ni<4;ni++){
        float bv = bias[n0+wn+ni*16+r16];
        int d = ni*16 + r16;
        #pragma unroll
        for(int mi=0;mi<4;mi++)
          #pragma unroll
          for(int reg=0;reg<4;reg++){
            int tt = mi*16 + g*4 + reg;
            dst[(size_t)tt*HEADv + d] = f2bf((acc[mi][ni][reg] + bv)*scale);
          }
      }
    } else {
      unsigned short* dst = base + 2ll*BT*N_EMBD
                          + (((size_t)bb*N_HEADv + h)*HEADv)*Tv + tt0;
      #pragma unroll
      for(int ni=0;ni<4;ni++){
        float bv = bias[n0+wn+ni*16+r16];
        int d = ni*16 + r16;
        #pragma unroll
        for(int mi=0;mi<4;mi++)
          #pragma unroll
          for(int reg=0;reg<4;reg++){
            int tt = mi*16 + g*4 + reg;
            dst[(size_t)d*Tv + tt] = f2bf(acc[mi][ni][reg] + bv);
          }
      }
    }
  } else {
    float* out = (float*)Cout;
    #pragma unroll
    for(int mi=0;mi<4;mi++){
      int m = m0+wm+mi*16+r16;
      #pragma unroll
      for(int ni=0;ni<4;ni++){
        int n = n0+wn+ni*16+g*4;
        float4 b4 = *reinterpret_cast<const float4*>(&bias[n]);
        float4 o4;
        o4.x = acc[mi][ni][0] + b4.x;
        o4.y = acc[mi][ni][1] + b4.y;
        o4.z = acc[mi][ni][2] + b4.z;
        o4.w = acc[mi][ni][3] + b4.w;
        *reinterpret_cast<float4*>(&out[(size_t)m*N + n]) = o4;
      }
    }
  }
}

// ---------------- flash attention (causal), split-K chunks ----------------
// Q pre-scaled by (1/8)log2e -> sacc is directly in exp2 domain.
// Speculative exp2 (no max-tree dep) + rare repair branch; l via ones-MFMA.
__global__ __launch_bounds__(256) void k_attn(
    const unsigned short* __restrict__ QKV,
    unsigned short* __restrict__ O,
    unsigned short* __restrict__ partO,
    float2* __restrict__ stats)
{
  __shared__ unsigned short Ks[2][64][64];   // [buf][key][d], swizzled cols
  __shared__ unsigned short Vs[2][64][64];   // [buf][d][key]
  __shared__ unsigned short Ps[4][16][64];   // [wave][q][key]
  int blk = blockIdx.x;
  int bh = blk & 31;
  int j  = blk >> 5;
  int qt, kt0, ktN; bool single;
  if(j < 16)      { qt = 16+j;  kt0 = 0;  ktN = 16;    single = false; }
  else if(j < 32) { qt = 47-j;  kt0 = 16; ktN = qt+1;  single = false; }
  else            { qt = 47-j;  kt0 = 0;  ktN = qt+1;  single = true;  }

  int t = threadIdx.x, lane=t&63, wid=t>>6;
  int g = lane>>4, r16 = lane&15;
  const unsigned short* Qp  = QKV + (size_t)bh*Tv*HEADv;
  const unsigned short* Kp  = QKV + (size_t)BT*N_EMBD + (size_t)bh*Tv*HEADv;
  const unsigned short* Vtp = QKV + 2ll*BT*N_EMBD + (size_t)bh*HEADv*Tv;
  int q0 = qt*64 + wid*16;

  bf16x8 aq[2];   // B-operand: col = q = r16
  #pragma unroll
  for(int kb=0;kb<2;kb++)
    aq[kb] = *reinterpret_cast<const bf16x8*>(&Qp[(size_t)(q0+r16)*HEADv + kb*32 + g*8]);

  const short ONE = (short)0x3F80;           // bf16 1.0
  const bf16x8 ones8 = {ONE,ONE,ONE,ONE,ONE,ONE,ONE,ONE};

  f32x4 oacc[4] = {};
  f32x4 lacc = {};            // l via ones-MFMA (element 0 used)
  float m2 = 6.0f;            // warm init (log2 domain)

  // staging: thread covers rows t>>3 and t>>3+32, 16B slot t&7
  int r0 = t>>3, c0 = (t&7)*8;
  int r1 = r0 + 32;
  int sw0 = c0 ^ ((r0&7)<<3);
  int sw1 = c0 ^ ((r1&7)<<3);
  int rsw = (r16&7)<<3;

  // prologue: tile kt0 -> regs -> buf0 ; issue tile kt0+1 loads
  int4 kc0, kc1, vc0, vc1;
  kc0 = *reinterpret_cast<const int4*>(&Kp [(size_t)(kt0*64+r0)*HEADv + c0]);
  kc1 = *reinterpret_cast<const int4*>(&Kp [(size_t)(kt0*64+r1)*HEADv + c0]);
  vc0 = *reinterpret_cast<const int4*>(&Vtp[(size_t)r0*Tv + kt0*64 + c0]);
  vc1 = *reinterpret_cast<const int4*>(&Vtp[(size_t)r1*Tv + kt0*64 + c0]);
  *reinterpret_cast<int4*>(&Ks[0][r0][sw0]) = kc0;
  *reinterpret_cast<int4*>(&Ks[0][r1][sw1]) = kc1;
  *reinterpret_cast<int4*>(&Vs[0][r0][sw0]) = vc0;
  *reinterpret_cast<int4*>(&Vs[0][r1][sw1]) = vc1;
  if(ktN - kt0 > 1){
    kc0 = *reinterpret_cast<const int4*>(&Kp [(size_t)((kt0+1)*64+r0)*HEADv + c0]);
    kc1 = *reinterpret_cast<const int4*>(&Kp [(size_t)((kt0+1)*64+r1)*HEADv + c0]);
    vc0 = *reinterpret_cast<const int4*>(&Vtp[(size_t)r0*Tv + (kt0+1)*64 + c0]);
    vc1 = *reinterpret_cast<const int4*>(&Vtp[(size_t)r1*Tv + (kt0+1)*64 + c0]);
  }
  __syncthreads();

  for(int kt=kt0; kt<ktN; ++kt){
    int cur = kt & 1;
    if(kt+1 < ktN){
      *reinterpret_cast<int4*>(&Ks[cur^1][r0][sw0]) = kc0;
      *reinterpret_cast<int4*>(&Ks[cur^1][r1][sw1]) = kc1;
      *reinterpret_cast<int4*>(&Vs[cur^1][r0][sw0]) = vc0;
      *reinterpret_cast<int4*>(&Vs[cur^1][r1][sw1]) = vc1;
      if(kt+2 < ktN){
        kc0 = *reinterpret_cast<const int4*>(&Kp [(size_t)((kt+2)*64+r0)*HEADv + c0]);
        kc1 = *reinterpret_cast<const int4*>(&Kp [(size_t)((kt+2)*64+r1)*HEADv + c0]);
        vc0 = *reinterpret_cast<const int4*>(&Vtp[(size_t)r0*Tv + (kt+2)*64 + c0]);
        vc1 = *reinterpret_cast<const int4*>(&Vtp[(size_t)r1*Tv + (kt+2)*64 + c0]);
      }
    }

    // S^T (already exp2-domain): sacc[nb][reg] = S[q=q0+r16][key = kt*64+nb*16+g*4+reg]
    f32x4 sacc[4];
    __builtin_amdgcn_s_setprio(1);
    #pragma unroll
    for(int nb=0;nb<4;nb++){
      sacc[nb] = (f32x4){0.f,0.f,0.f,0.f};
      #pragma unroll
      for(int kb=0;kb<2;kb++){
        bf16x8 bk = *reinterpret_cast<const bf16x8*>(&Ks[cur][nb*16+r16][(kb*32+g*8) ^ rsw]);
        sacc[nb] = __builtin_amdgcn_mfma_f32_16x16x32_bf16(bk, aq[kb], sacc[nb],0,0,0);
      }
    }
    __builtin_amdgcn_s_setprio(0);

    bool diag = (kt == qt);
    float sv[4][4], pv[4][4];
    #pragma unroll
    for(int nb=0;nb<4;nb++)
      #pragma unroll
      for(int reg=0;reg<4;reg++){
        float s = sacc[nb][reg];
        if(diag){
          int keyin = nb*16 + g*4 + reg;
          if(keyin > wid*16 + r16) s = -1e30f;
        }
        sv[nb][reg] = s;
      }
    // speculative exp2: no dependency on the row-max
    #pragma unroll
    for(int nb=0;nb<4;nb++)
      #pragma unroll
      for(int reg=0;reg<4;reg++)
        pv[nb][reg] = __builtin_amdgcn_exp2f(sv[nb][reg] - m2);

    // parallel path: row max -> rare repair branch
    float mxnb[4];
    #pragma unroll
    for(int nb=0;nb<4;nb++)
      mxnb[nb] = fmaxf(fmaxf(sv[nb][0],sv[nb][1]), fmaxf(sv[nb][2],sv[nb][3]));
    float mx = fmaxf(fmaxf(mxnb[0],mxnb[1]), fmaxf(mxnb[2],mxnb[3]));
    mx = fmaxf(mx, __shfl_xor(mx, 16, 64));
    mx = fmaxf(mx, __shfl_xor(mx, 32, 64));

    if(!__all(mx - m2 <= 11.5f)){
      float mn = fmaxf(m2, mx);
      float alpha = __builtin_amdgcn_exp2f(m2 - mn);
      lacc[0]*=alpha; lacc[1]*=alpha; lacc[2]*=alpha; lacc[3]*=alpha;
      #pragma unroll
      for(int nb=0;nb<4;nb++)
        #pragma unroll
        for(int reg=0;reg<4;reg++) oacc[nb][reg] *= alpha;
      m2 = mn;
      #pragma unroll
      for(int nb=0;nb<4;nb++)
        #pragma unroll
        for(int reg=0;reg<4;reg++)
          pv[nb][reg] = __builtin_amdgcn_exp2f(sv[nb][reg] - m2);
    }

    #pragma unroll
    for(int nb=0;nb<4;nb++){
      union { uint32_t u[2]; int2 v; } w;
      w.u[0] = f2bf_fast(pv[nb][0]) | (f2bf_fast(pv[nb][1])<<16);
      w.u[1] = f2bf_fast(pv[nb][2]) | (f2bf_fast(pv[nb][3])<<16);
      *reinterpret_cast<int2*>(&Ps[wid][r16][(nb*16+g*4) ^ rsw]) = w.v;
    }

    // PV (+ l via ones-MFMA): contraction over keys handles cross-lane sum
    __builtin_amdgcn_s_setprio(1);
    #pragma unroll
    for(int kb=0;kb<2;kb++){
      bf16x8 ap = *reinterpret_cast<const bf16x8*>(&Ps[wid][r16][(kb*32+g*8) ^ rsw]);
      lacc = __builtin_amdgcn_mfma_f32_16x16x32_bf16(ones8, ap, lacc,0,0,0);
      #pragma unroll
      for(int nb=0;nb<4;nb++){
        bf16x8 bv = *reinterpret_cast<const bf16x8*>(&Vs[cur][nb*16+r16][(kb*32+g*8) ^ rsw]);
        oacc[nb] = __builtin_amdgcn_mfma_f32_16x16x32_bf16(bv, ap, oacc[nb],0,0,0);
      }
    }
    __builtin_amdgcn_s_setprio(0);
    __syncthreads();
  }

  float l = lacc[0];
  float rinv = 1.0f / l;
  if(single){
    int b = bh >> 4, h = bh & 15;
    size_t row = (size_t)b*Tv + q0 + r16;
    #pragma unroll
    for(int nb=0;nb<4;nb++){
      ushort4 o;
      o.x = f2bf(oacc[nb][0]*rinv);
      o.y = f2bf(oacc[nb][1]*rinv);
      o.z = f2bf(oacc[nb][2]*rinv);
      o.w = f2bf(oacc[nb][3]*rinv);
      *reinterpret_cast<ushort4*>(&O[row*N_EMBD + h*HEADv + nb*16 + g*4]) = o;
    }
  } else {
    int part = j*32 + bh;
    unsigned short* po = partO + (size_t)part*4096;
    int qloc = wid*16 + r16;
    #pragma unroll
    for(int nb=0;nb<4;nb++){
      ushort4 o;
      o.x = f2bf(oacc[nb][0]*rinv);
      o.y = f2bf(oacc[nb][1]*rinv);
      o.z = f2bf(oacc[nb][2]*rinv);
      o.w = f2bf(oacc[nb][3]*rinv);
      *reinterpret_cast<ushort4*>(&po[qloc*64 + nb*16 + g*4]) = o;
    }
    if(g==0) stats[part*64 + qloc] = make_float2(m2, l);
  }
}

// ---------------- merge two partials per (bh, qt>=16) ----------------
__global__ __launch_bounds__(256) void k_merge(
    const unsigned short* __restrict__ partO,
    const float2* __restrict__ stats,
    unsigned short* __restrict__ O)
{
  int blk = blockIdx.x;            // 512
  int bh = blk & 31, qt = 16 + (blk >> 5);
  int p0 = (qt-16)*32 + bh;
  int p1 = (47-qt)*32 + bh;
  int t = threadIdx.x;
  int q = t >> 2, d0 = (t&3)*16;
  float2 s0 = stats[p0*64 + q];
  float2 s1 = stats[p1*64 + q];
  float m = fmaxf(s0.x, s1.x);
  float w0 = s0.y * __builtin_amdgcn_exp2f(s0.x - m);
  float w1 = s1.y * __builtin_amdgcn_exp2f(s1.x - m);
  float rinv = 1.f/(w0+w1);
  w0 *= rinv; w1 *= rinv;
  const unsigned short* a = partO + (size_t)p0*4096 + q*64 + d0;
  const unsigned short* b = partO + (size_t)p1*4096 + q*64 + d0;
  int bb = bh >> 4, h = bh & 15;
  unsigned short* o = O + ((size_t)bb*Tv + qt*64 + q)*N_EMBD + h*HEADv + d0;
  #pragma unroll
  for(int half=0; half<2; ++half){
    union { int4 v; unsigned short s[8]; } ua, ub, uo;
    ua.v = *reinterpret_cast<const int4*>(a + half*8);
    ub.v = *reinterpret_cast<const int4*>(b + half*8);
    #pragma unroll
    for(int e=0;e<8;e++)
      uo.s[e] = f2bf(bf2f(ua.s[e])*w0 + bf2f(ub.s[e])*w1);
    *reinterpret_cast<int4*>(o + half*8) = uo.v;
  }
}

extern "C" void kernel_launch(void* const* d_in, const int* in_sizes, int n_in,
                              void* d_out, int out_size, void* d_ws, size_t ws_size,
                              hipStream_t stream){
  const float* x      = (const float*)d_in[0];
  const float* w_attn = (const float*)d_in[1];
  const float* b_attn = (const float*)d_in[2];
  const float* w_proj = (const float*)d_in[3];
  const float* b_proj = (const float*)d_in[4];
  char* ws = (char*)d_ws;
  unsigned short* xb  = (unsigned short*)ws;                        // 8 MB  (dead after gemm0 -> partO)
  unsigned short* qkv = (unsigned short*)(ws + 8ll*1024*1024);      // 24 MB (V third stored transposed)
  unsigned short* ob  = (unsigned short*)(ws + 32ll*1024*1024);     // 8 MB
  unsigned short* wat = (unsigned short*)(ws + 40ll*1024*1024);     // 6 MB  (dead after gemm0 -> stats)
  unsigned short* wpt = (unsigned short*)(ws + 46ll*1024*1024);     // 2 MB
  unsigned short* partO = xb;                                       // 1024 * 8KB = 8 MB
  float2*        stats  = (float2*)wat;                             // 1024 * 512B = 512 KB

  k_prep<<<dim3(3072),256,0,stream>>>(x, xb, w_attn, wat, w_proj, wpt);
  k_gemm<0><<<dim3(C3/128, BT/128),256,0,stream>>>(xb, wat, b_attn, (void*)qkv, BT, C3, N_EMBD);
  k_attn<<<dim3(48*32),256,0,stream>>>(qkv, ob, partO, stats);
  k_merge<<<dim3(512),256,0,stream>>>(partO, stats, ob);
  k_gemm<1><<<dim3(N_EMBD/128, BT/128),256,0,stream>>>(ob, wpt, b_proj, d_out, BT, N_EMBD, N_EMBD);
}

// Round 13
// 109.542 us; speedup vs baseline: 1.2460x; 1.0714x over previous
//
#include <hip/hip_runtime.h>
#include <stdint.h>

#define N_EMBD 1024
#define N_HEADv 16
#define HEADv 64
#define Bv 2
#define Tv 2048
#define BT (Bv*Tv)      // 4096
#define C3 (3*N_EMBD)   // 3072

typedef __attribute__((ext_vector_type(8))) short bf16x8;
typedef __attribute__((ext_vector_type(4))) float f32x4;

typedef __attribute__((address_space(3))) uint32_t lds_u32;
typedef const __attribute__((address_space(1))) uint32_t glb_u32;

__device__ __forceinline__ void gload_lds16(const void* g, void* l){
  __builtin_amdgcn_global_load_lds((glb_u32*)g, (lds_u32*)l, 16, 0, 0);
}

__device__ __forceinline__ unsigned short f2bf(float f){
  union { float f; uint32_t u; } v; v.f = f;
  uint32_t u = v.u;
  uint32_t r = u + 0x7FFFu + ((u>>16)&1u);
  return (unsigned short)(r>>16);
}
__device__ __forceinline__ uint32_t f2bf_fast(float f){
  union { float f; uint32_t u; } v; v.f = f;
  return (v.u + 0x8000u) >> 16;
}
__device__ __forceinline__ float bf2f(unsigned short s){
  union { uint32_t u; float f; } v; v.u = ((uint32_t)s)<<16; return v.f;
}

// ---------------- fused prep: x->bf16 cvt + both weight transposes ----------------
__global__ __launch_bounds__(256) void k_prep(
    const float* __restrict__ x, unsigned short* __restrict__ xb,
    const float* __restrict__ w_attn, unsigned short* __restrict__ wat,
    const float* __restrict__ w_proj, unsigned short* __restrict__ wpt)
{
  __shared__ float tile[64][65];
  int blk = blockIdx.x;
  int t = threadIdx.x;
  if(blk < 2048){
    long i = ((long)blk*256 + t)*8;
    float4 a = *reinterpret_cast<const float4*>(x+i);
    float4 b = *reinterpret_cast<const float4*>(x+i+4);
    union { int4 v; unsigned short s[8]; } o;
    o.s[0]=f2bf(a.x); o.s[1]=f2bf(a.y); o.s[2]=f2bf(a.z); o.s[3]=f2bf(a.w);
    o.s[4]=f2bf(b.x); o.s[5]=f2bf(b.y); o.s[6]=f2bf(b.z); o.s[7]=f2bf(b.w);
    *reinterpret_cast<int4*>(xb+i) = o.v;
  } else {
    const float* in; unsigned short* out; int K, N, n0, k0;
    if(blk < 2816){
      int b = blk - 2048;
      in = w_attn; out = wat; K = N_EMBD; N = C3;
      n0 = (b % 48)*64; k0 = (b / 48)*64;
    } else {
      int b = blk - 2816;
      in = w_proj; out = wpt; K = N_EMBD; N = N_EMBD;
      n0 = (b % 16)*64; k0 = (b / 16)*64;
    }
    #pragma unroll
    for(int p=0;p<4;p++){
      int row = (t>>4) + p*16;
      int col4 = (t&15)*4;
      float4 v = *reinterpret_cast<const float4*>(&in[(size_t)(k0+row)*N + n0 + col4]);
      tile[row][col4+0]=v.x; tile[row][col4+1]=v.y; tile[row][col4+2]=v.z; tile[row][col4+3]=v.w;
    }
    __syncthreads();
    #pragma unroll
    for(int p=0;p<4;p++){
      int nrow = (t>>4) + p*16;
      int kc = (t&15)*4;
      ushort4 o;
      o.x = f2bf(tile[kc+0][nrow]);
      o.y = f2bf(tile[kc+1][nrow]);
      o.z = f2bf(tile[kc+2][nrow]);
      o.w = f2bf(tile[kc+3][nrow]);
      *reinterpret_cast<ushort4*>(&out[(size_t)(n0+nrow)*K + k0 + kc]) = o;
    }
  }
}

// ---------------- bf16 MFMA GEMM: C = A[M][K] @ Bt[N][K]^T + bias ----------------
// Tile = (FM*32) x (FN*32), 4 waves in 2x2; FM=FN=4 reproduces the r12 kernel.
// T3-minimum 2-phase dbuf, gload_lds issue-next-first, one barrier/iter.
// BK=64, 128B LDS rows, row&7 XOR swizzle (row-local, FM/FN-independent).
// MODE 0: scatter Q*SC,K -> [b,h,t,d]; V -> [b,h,d,t] (fused transpose).
// MODE 1: fp32 out [M][N], swapped-operand D^T epilogue -> float4 stores.
template<int MODE, int FM, int FN>
__global__ __launch_bounds__(256) void k_gemm(
    const unsigned short* __restrict__ A,
    const unsigned short* __restrict__ Bt,
    const float* __restrict__ bias,
    void* __restrict__ Cout,
    int M, int N, int K)
{
  const int BK=64;
  const int TM=FM*32, TN=FN*32;
  const int ASZ=TM*BK, BSZ=TN*BK;
  __shared__ unsigned short As[2*ASZ];
  __shared__ unsigned short Bs[2*BSZ];
  int m0 = blockIdx.y*TM, n0 = blockIdx.x*TN;
  int t = threadIdx.x, lane = t&63, wid = t>>6;
  int wm = (wid>>1)*FM*16, wn = (wid&1)*FN*16;
  int g = lane>>4, r16 = lane&15;
  int rl  = lane>>3;                 // 0..7 = row&7
  int cle = (((lane&7) ^ rl) * 8);   // inverse-swizzled col (bf16 elems)
  int rsw = r16 & 7;                 // read-side row swizzle key
  f32x4 acc[FM][FN] = {};

  // prologue: stage tile 0 into buffer 0
  #pragma unroll
  for(int c=0;c<FM;c++){
    int rb = wid*FM*8 + c*8;
    gload_lds16(&A [(size_t)(m0+rb+rl)*K + cle], &As[rb*BK]);
  }
  #pragma unroll
  for(int c=0;c<FN;c++){
    int rb = wid*FN*8 + c*8;
    gload_lds16(&Bt[(size_t)(n0+rb+rl)*K + cle], &Bs[rb*BK]);
  }
  __syncthreads();

  const int NIT = K/BK;
  for(int it=0; it<NIT; ++it){
    int cur = it & 1;
    // issue next tile's loads FIRST -> in flight during compute (T3/T14)
    if(it+1 < NIT){
      int k0 = (it+1)*BK;
      #pragma unroll
      for(int c=0;c<FM;c++){
        int rb = wid*FM*8 + c*8;
        gload_lds16(&A [(size_t)(m0+rb+rl)*K + k0 + cle], &As[(cur^1)*ASZ + rb*BK]);
      }
      #pragma unroll
      for(int c=0;c<FN;c++){
        int rb = wid*FN*8 + c*8;
        gload_lds16(&Bt[(size_t)(n0+rb+rl)*K + k0 + cle], &Bs[(cur^1)*BSZ + rb*BK]);
      }
    }
    const unsigned short* Ab = &As[cur*ASZ];
    const unsigned short* Bb = &Bs[cur*BSZ];
    bf16x8 af[2][FM], bfr[2][FN];
    #pragma unroll
    for(int ks=0;ks<2;ks++){
      #pragma unroll
      for(int mi=0;mi<FM;mi++)
        af[ks][mi]  = *reinterpret_cast<const bf16x8*>(&Ab[(wm+mi*16+r16)*BK + (((ks*4+g)^rsw)*8)]);
      #pragma unroll
      for(int ni=0;ni<FN;ni++)
        bfr[ks][ni] = *reinterpret_cast<const bf16x8*>(&Bb[(wn+ni*16+r16)*BK + (((ks*4+g)^rsw)*8)]);
    }
    __builtin_amdgcn_s_setprio(1);
    #pragma unroll
    for(int ks=0;ks<2;ks++)
      #pragma unroll
      for(int mi=0;mi<FM;mi++)
        #pragma unroll
        for(int ni=0;ni<FN;ni++){
          if(MODE==0)
            acc[mi][ni] = __builtin_amdgcn_mfma_f32_16x16x32_bf16(af[ks][mi], bfr[ks][ni], acc[mi][ni], 0,0,0);
          else
            acc[mi][ni] = __builtin_amdgcn_mfma_f32_16x16x32_bf16(bfr[ks][ni], af[ks][mi], acc[mi][ni], 0,0,0);
        }
    __builtin_amdgcn_s_setprio(0);
    __syncthreads();   // drains next-tile gloads (had full compute phase in flight)
  }

  if(MODE==0){
    int which = (n0+wn)>>10;
    int h = ((n0+wn)&1023)>>6;
    int bb = m0>>11;
    int tt0 = (m0&2047) + wm;
    unsigned short* base = (unsigned short*)Cout;
    if(which < 2){
      // Q pre-scaled by (1/8)*log2(e) so attn uses sacc directly in exp2 domain
      float scale = (which==0) ? 0.18033688f : 1.0f;   // wave-uniform
      unsigned short* dst = base + (size_t)which*BT*N_EMBD
                          + (((size_t)bb*N_HEADv + h)*Tv + tt0)*HEADv;
      #pragma unroll
      for(int ni=0;ni<FN;ni++){
        float bv = bias[n0+wn+ni*16+r16];
        int d = ni*16 + r16;
        #pragma unroll
        for(int mi=0;mi<FM;mi++)
          #pragma unroll
          for(int reg=0;reg<4;reg++){
            int tt = mi*16 + g*4 + reg;
            dst[(size_t)tt*HEADv + d] = f2bf((acc[mi][ni][reg] + bv)*scale);
          }
      }
    } else {
      unsigned short* dst = base + 2ll*BT*N_EMBD
                          + (((size_t)bb*N_HEADv + h)*HEADv)*Tv + tt0;
      #pragma unroll
      for(int ni=0;ni<FN;ni++){
        float bv = bias[n0+wn+ni*16+r16];
        int d = ni*16 + r16;
        #pragma unroll
        for(int mi=0;mi<FM;mi++)
          #pragma unroll
          for(int reg=0;reg<4;reg++){
            int tt = mi*16 + g*4 + reg;
            dst[(size_t)d*Tv + tt] = f2bf(acc[mi][ni][reg] + bv);
          }
      }
    }
  } else {
    float* out = (float*)Cout;
    #pragma unroll
    for(int mi=0;mi<FM;mi++){
      int m = m0+wm+mi*16+r16;
      #pragma unroll
      for(int ni=0;ni<FN;ni++){
        int n = n0+wn+ni*16+g*4;
        float4 b4 = *reinterpret_cast<const float4*>(&bias[n]);
        float4 o4;
        o4.x = acc[mi][ni][0] + b4.x;
        o4.y = acc[mi][ni][1] + b4.y;
        o4.z = acc[mi][ni][2] + b4.z;
        o4.w = acc[mi][ni][3] + b4.w;
        *reinterpret_cast<float4*>(&out[(size_t)m*N + n]) = o4;
      }
    }
  }
}

// ---------------- flash attention (causal), split-K chunks ----------------
// Q pre-scaled by (1/8)log2e -> sacc is directly in exp2 domain.
// Speculative exp2 (no max-tree dep) + rare repair branch; l via ones-MFMA.
__global__ __launch_bounds__(256) void k_attn(
    const unsigned short* __restrict__ QKV,
    unsigned short* __restrict__ O,
    unsigned short* __restrict__ partO,
    float2* __restrict__ stats)
{
  __shared__ unsigned short Ks[2][64][64];   // [buf][key][d], swizzled cols
  __shared__ unsigned short Vs[2][64][64];   // [buf][d][key]
  __shared__ unsigned short Ps[4][16][64];   // [wave][q][key]
  int blk = blockIdx.x;
  int bh = blk & 31;
  int j  = blk >> 5;
  int qt, kt0, ktN; bool single;
  if(j < 16)      { qt = 16+j;  kt0 = 0;  ktN = 16;    single = false; }
  else if(j < 32) { qt = 47-j;  kt0 = 16; ktN = qt+1;  single = false; }
  else            { qt = 47-j;  kt0 = 0;  ktN = qt+1;  single = true;  }

  int t = threadIdx.x, lane=t&63, wid=t>>6;
  int g = lane>>4, r16 = lane&15;
  const unsigned short* Qp  = QKV + (size_t)bh*Tv*HEADv;
  const unsigned short* Kp  = QKV + (size_t)BT*N_EMBD + (size_t)bh*Tv*HEADv;
  const unsigned short* Vtp = QKV + 2ll*BT*N_EMBD + (size_t)bh*HEADv*Tv;
  int q0 = qt*64 + wid*16;

  bf16x8 aq[2];   // B-operand: col = q = r16
  #pragma unroll
  for(int kb=0;kb<2;kb++)
    aq[kb] = *reinterpret_cast<const bf16x8*>(&Qp[(size_t)(q0+r16)*HEADv + kb*32 + g*8]);

  const short ONE = (short)0x3F80;           // bf16 1.0
  const bf16x8 ones8 = {ONE,ONE,ONE,ONE,ONE,ONE,ONE,ONE};

  f32x4 oacc[4] = {};
  f32x4 lacc = {};            // l via ones-MFMA (element 0 used)
  float m2 = 6.0f;            // warm init (log2 domain)

  // staging: thread covers rows t>>3 and t>>3+32, 16B slot t&7
  int r0 = t>>3, c0 = (t&7)*8;
  int r1 = r0 + 32;
  int sw0 = c0 ^ ((r0&7)<<3);
  int sw1 = c0 ^ ((r1&7)<<3);
  int rsw = (r16&7)<<3;

  // prologue: tile kt0 -> regs -> buf0 ; issue tile kt0+1 loads
  int4 kc0, kc1, vc0, vc1;
  kc0 = *reinterpret_cast<const int4*>(&Kp [(size_t)(kt0*64+r0)*HEADv + c0]);
  kc1 = *reinterpret_cast<const int4*>(&Kp [(size_t)(kt0*64+r1)*HEADv + c0]);
  vc0 = *reinterpret_cast<const int4*>(&Vtp[(size_t)r0*Tv + kt0*64 + c0]);
  vc1 = *reinterpret_cast<const int4*>(&Vtp[(size_t)r1*Tv + kt0*64 + c0]);
  *reinterpret_cast<int4*>(&Ks[0][r0][sw0]) = kc0;
  *reinterpret_cast<int4*>(&Ks[0][r1][sw1]) = kc1;
  *reinterpret_cast<int4*>(&Vs[0][r0][sw0]) = vc0;
  *reinterpret_cast<int4*>(&Vs[0][r1][sw1]) = vc1;
  if(ktN - kt0 > 1){
    kc0 = *reinterpret_cast<const int4*>(&Kp [(size_t)((kt0+1)*64+r0)*HEADv + c0]);
    kc1 = *reinterpret_cast<const int4*>(&Kp [(size_t)((kt0+1)*64+r1)*HEADv + c0]);
    vc0 = *reinterpret_cast<const int4*>(&Vtp[(size_t)r0*Tv + (kt0+1)*64 + c0]);
    vc1 = *reinterpret_cast<const int4*>(&Vtp[(size_t)r1*Tv + (kt0+1)*64 + c0]);
  }
  __syncthreads();

  for(int kt=kt0; kt<ktN; ++kt){
    int cur = kt & 1;
    if(kt+1 < ktN){
      *reinterpret_cast<int4*>(&Ks[cur^1][r0][sw0]) = kc0;
      *reinterpret_cast<int4*>(&Ks[cur^1][r1][sw1]) = kc1;
      *reinterpret_cast<int4*>(&Vs[cur^1][r0][sw0]) = vc0;
      *reinterpret_cast<int4*>(&Vs[cur^1][r1][sw1]) = vc1;
      if(kt+2 < ktN){
        kc0 = *reinterpret_cast<const int4*>(&Kp [(size_t)((kt+2)*64+r0)*HEADv + c0]);
        kc1 = *reinterpret_cast<const int4*>(&Kp [(size_t)((kt+2)*64+r1)*HEADv + c0]);
        vc0 = *reinterpret_cast<const int4*>(&Vtp[(size_t)r0*Tv + (kt+2)*64 + c0]);
        vc1 = *reinterpret_cast<const int4*>(&Vtp[(size_t)r1*Tv + (kt+2)*64 + c0]);
      }
    }

    // S^T (already exp2-domain): sacc[nb][reg] = S[q=q0+r16][key = kt*64+nb*16+g*4+reg]
    f32x4 sacc[4];
    __builtin_amdgcn_s_setprio(1);
    #pragma unroll
    for(int nb=0;nb<4;nb++){
      sacc[nb] = (f32x4){0.f,0.f,0.f,0.f};
      #pragma unroll
      for(int kb=0;kb<2;kb++){
        bf16x8 bk = *reinterpret_cast<const bf16x8*>(&Ks[cur][nb*16+r16][(kb*32+g*8) ^ rsw]);
        sacc[nb] = __builtin_amdgcn_mfma_f32_16x16x32_bf16(bk, aq[kb], sacc[nb],0,0,0);
      }
    }
    __builtin_amdgcn_s_setprio(0);

    bool diag = (kt == qt);
    float sv[4][4], pv[4][4];
    #pragma unroll
    for(int nb=0;nb<4;nb++)
      #pragma unroll
      for(int reg=0;reg<4;reg++){
        float s = sacc[nb][reg];
        if(diag){
          int keyin = nb*16 + g*4 + reg;
          if(keyin > wid*16 + r16) s = -1e30f;
        }
        sv[nb][reg] = s;
      }
    // speculative exp2: no dependency on the row-max
    #pragma unroll
    for(int nb=0;nb<4;nb++)
      #pragma unroll
      for(int reg=0;reg<4;reg++)
        pv[nb][reg] = __builtin_amdgcn_exp2f(sv[nb][reg] - m2);

    // parallel path: row max -> rare repair branch
    float mxnb[4];
    #pragma unroll
    for(int nb=0;nb<4;nb++)
      mxnb[nb] = fmaxf(fmaxf(sv[nb][0],sv[nb][1]), fmaxf(sv[nb][2],sv[nb][3]));
    float mx = fmaxf(fmaxf(mxnb[0],mxnb[1]), fmaxf(mxnb[2],mxnb[3]));
    mx = fmaxf(mx, __shfl_xor(mx, 16, 64));
    mx = fmaxf(mx, __shfl_xor(mx, 32, 64));

    if(!__all(mx - m2 <= 11.5f)){
      float mn = fmaxf(m2, mx);
      float alpha = __builtin_amdgcn_exp2f(m2 - mn);
      lacc[0]*=alpha; lacc[1]*=alpha; lacc[2]*=alpha; lacc[3]*=alpha;
      #pragma unroll
      for(int nb=0;nb<4;nb++)
        #pragma unroll
        for(int reg=0;reg<4;reg++) oacc[nb][reg] *= alpha;
      m2 = mn;
      #pragma unroll
      for(int nb=0;nb<4;nb++)
        #pragma unroll
        for(int reg=0;reg<4;reg++)
          pv[nb][reg] = __builtin_amdgcn_exp2f(sv[nb][reg] - m2);
    }

    #pragma unroll
    for(int nb=0;nb<4;nb++){
      union { uint32_t u[2]; int2 v; } w;
      w.u[0] = f2bf_fast(pv[nb][0]) | (f2bf_fast(pv[nb][1])<<16);
      w.u[1] = f2bf_fast(pv[nb][2]) | (f2bf_fast(pv[nb][3])<<16);
      *reinterpret_cast<int2*>(&Ps[wid][r16][(nb*16+g*4) ^ rsw]) = w.v;
    }

    // PV (+ l via ones-MFMA): contraction over keys handles cross-lane sum
    __builtin_amdgcn_s_setprio(1);
    #pragma unroll
    for(int kb=0;kb<2;kb++){
      bf16x8 ap = *reinterpret_cast<const bf16x8*>(&Ps[wid][r16][(kb*32+g*8) ^ rsw]);
      lacc = __builtin_amdgcn_mfma_f32_16x16x32_bf16(ones8, ap, lacc,0,0,0);
      #pragma unroll
      for(int nb=0;nb<4;nb++){
        bf16x8 bv = *reinterpret_cast<const bf16x8*>(&Vs[cur][nb*16+r16][(kb*32+g*8) ^ rsw]);
        oacc[nb] = __builtin_amdgcn_mfma_f32_16x16x32_bf16(bv, ap, oacc[nb],0,0,0);
      }
    }
    __builtin_amdgcn_s_setprio(0);
    __syncthreads();
  }

  float l = lacc[0];
  float rinv = 1.0f / l;
  if(single){
    int b = bh >> 4, h = bh & 15;
    size_t row = (size_t)b*Tv + q0 + r16;
    #pragma unroll
    for(int nb=0;nb<4;nb++){
      ushort4 o;
      o.x = f2bf(oacc[nb][0]*rinv);
      o.y = f2bf(oacc[nb][1]*rinv);
      o.z = f2bf(oacc[nb][2]*rinv);
      o.w = f2bf(oacc[nb][3]*rinv);
      *reinterpret_cast<ushort4*>(&O[row*N_EMBD + h*HEADv + nb*16 + g*4]) = o;
    }
  } else {
    int part = j*32 + bh;
    unsigned short* po = partO + (size_t)part*4096;
    int qloc = wid*16 + r16;
    #pragma unroll
    for(int nb=0;nb<4;nb++){
      ushort4 o;
      o.x = f2bf(oacc[nb][0]*rinv);
      o.y = f2bf(oacc[nb][1]*rinv);
      o.z = f2bf(oacc[nb][2]*rinv);
      o.w = f2bf(oacc[nb][3]*rinv);
      *reinterpret_cast<ushort4*>(&po[qloc*64 + nb*16 + g*4]) = o;
    }
    if(g==0) stats[part*64 + qloc] = make_float2(m2, l);
  }
}

// ---------------- merge two partials per (bh, qt>=16) ----------------
__global__ __launch_bounds__(256) void k_merge(
    const unsigned short* __restrict__ partO,
    const float2* __restrict__ stats,
    unsigned short* __restrict__ O)
{
  int blk = blockIdx.x;            // 512
  int bh = blk & 31, qt = 16 + (blk >> 5);
  int p0 = (qt-16)*32 + bh;
  int p1 = (47-qt)*32 + bh;
  int t = threadIdx.x;
  int q = t >> 2, d0 = (t&3)*16;
  float2 s0 = stats[p0*64 + q];
  float2 s1 = stats[p1*64 + q];
  float m = fmaxf(s0.x, s1.x);
  float w0 = s0.y * __builtin_amdgcn_exp2f(s0.x - m);
  float w1 = s1.y * __builtin_amdgcn_exp2f(s1.x - m);
  float rinv = 1.f/(w0+w1);
  w0 *= rinv; w1 *= rinv;
  const unsigned short* a = partO + (size_t)p0*4096 + q*64 + d0;
  const unsigned short* b = partO + (size_t)p1*4096 + q*64 + d0;
  int bb = bh >> 4, h = bh & 15;
  unsigned short* o = O + ((size_t)bb*Tv + qt*64 + q)*N_EMBD + h*HEADv + d0;
  #pragma unroll
  for(int half=0; half<2; ++half){
    union { int4 v; unsigned short s[8]; } ua, ub, uo;
    ua.v = *reinterpret_cast<const int4*>(a + half*8);
    ub.v = *reinterpret_cast<const int4*>(b + half*8);
    #pragma unroll
    for(int e=0;e<8;e++)
      uo.s[e] = f2bf(bf2f(ua.s[e])*w0 + bf2f(ub.s[e])*w1);
    *reinterpret_cast<int4*>(o + half*8) = uo.v;
  }
}

extern "C" void kernel_launch(void* const* d_in, const int* in_sizes, int n_in,
                              void* d_out, int out_size, void* d_ws, size_t ws_size,
                              hipStream_t stream){
  const float* x      = (const float*)d_in[0];
  const float* w_attn = (const float*)d_in[1];
  const float* b_attn = (const float*)d_in[2];
  const float* w_proj = (const float*)d_in[3];
  const float* b_proj = (const float*)d_in[4];
  char* ws = (char*)d_ws;
  unsigned short* xb  = (unsigned short*)ws;                        // 8 MB  (dead after gemm0 -> partO)
  unsigned short* qkv = (unsigned short*)(ws + 8ll*1024*1024);      // 24 MB (V third stored transposed)
  unsigned short* ob  = (unsigned short*)(ws + 32ll*1024*1024);     // 8 MB
  unsigned short* wat = (unsigned short*)(ws + 40ll*1024*1024);     // 6 MB  (dead after gemm0 -> stats)
  unsigned short* wpt = (unsigned short*)(ws + 46ll*1024*1024);     // 2 MB
  unsigned short* partO = xb;                                       // 1024 * 8KB = 8 MB
  float2*        stats  = (float2*)wat;                             // 1024 * 512B = 512 KB

  k_prep<<<dim3(3072),256,0,stream>>>(x, xb, w_attn, wat, w_proj, wpt);
  k_gemm<0,2,4><<<dim3(C3/128, BT/64),256,0,stream>>>(xb, wat, b_attn, (void*)qkv, BT, C3, N_EMBD);
  k_attn<<<dim3(48*32),256,0,stream>>>(qkv, ob, partO, stats);
  k_merge<<<dim3(512),256,0,stream>>>(partO, stats, ob);
  k_gemm<1,2,2><<<dim3(N_EMBD/64, BT/64),256,0,stream>>>(ob, wpt, b_proj, d_out, BT, N_EMBD, N_EMBD);
}

// Round 14
// 109.318 us; speedup vs baseline: 1.2485x; 1.0020x over previous
//
#include <hip/hip_runtime.h>
#include <stdint.h>

#define N_EMBD 1024
#define N_HEADv 16
#define HEADv 64
#define Bv 2
#define Tv 2048
#define BT (Bv*Tv)      // 4096
#define C3 (3*N_EMBD)   // 3072

typedef __attribute__((ext_vector_type(8))) short bf16x8;
typedef __attribute__((ext_vector_type(4))) float f32x4;

typedef __attribute__((address_space(3))) uint32_t lds_u32;
typedef const __attribute__((address_space(1))) uint32_t glb_u32;

__device__ __forceinline__ void gload_lds16(const void* g, void* l){
  __builtin_amdgcn_global_load_lds((glb_u32*)g, (lds_u32*)l, 16, 0, 0);
}

__device__ __forceinline__ unsigned short f2bf(float f){
  union { float f; uint32_t u; } v; v.f = f;
  uint32_t u = v.u;
  uint32_t r = u + 0x7FFFu + ((u>>16)&1u);
  return (unsigned short)(r>>16);
}
__device__ __forceinline__ uint32_t f2bf_fast(float f){
  union { float f; uint32_t u; } v; v.f = f;
  return (v.u + 0x8000u) >> 16;
}
__device__ __forceinline__ float bf2f(unsigned short s){
  union { uint32_t u; float f; } v; v.u = ((uint32_t)s)<<16; return v.f;
}

// ---------------- fused prep: x->bf16 cvt + both weight transposes ----------------
__global__ __launch_bounds__(256) void k_prep(
    const float* __restrict__ x, unsigned short* __restrict__ xb,
    const float* __restrict__ w_attn, unsigned short* __restrict__ wat,
    const float* __restrict__ w_proj, unsigned short* __restrict__ wpt)
{
  __shared__ float tile[64][65];
  int blk = blockIdx.x;
  int t = threadIdx.x;
  if(blk < 2048){
    long i = ((long)blk*256 + t)*8;
    float4 a = *reinterpret_cast<const float4*>(x+i);
    float4 b = *reinterpret_cast<const float4*>(x+i+4);
    union { int4 v; unsigned short s[8]; } o;
    o.s[0]=f2bf(a.x); o.s[1]=f2bf(a.y); o.s[2]=f2bf(a.z); o.s[3]=f2bf(a.w);
    o.s[4]=f2bf(b.x); o.s[5]=f2bf(b.y); o.s[6]=f2bf(b.z); o.s[7]=f2bf(b.w);
    *reinterpret_cast<int4*>(xb+i) = o.v;
  } else {
    const float* in; unsigned short* out; int K, N, n0, k0;
    if(blk < 2816){
      int b = blk - 2048;
      in = w_attn; out = wat; K = N_EMBD; N = C3;
      n0 = (b % 48)*64; k0 = (b / 48)*64;
    } else {
      int b = blk - 2816;
      in = w_proj; out = wpt; K = N_EMBD; N = N_EMBD;
      n0 = (b % 16)*64; k0 = (b / 16)*64;
    }
    #pragma unroll
    for(int p=0;p<4;p++){
      int row = (t>>4) + p*16;
      int col4 = (t&15)*4;
      float4 v = *reinterpret_cast<const float4*>(&in[(size_t)(k0+row)*N + n0 + col4]);
      tile[row][col4+0]=v.x; tile[row][col4+1]=v.y; tile[row][col4+2]=v.z; tile[row][col4+3]=v.w;
    }
    __syncthreads();
    #pragma unroll
    for(int p=0;p<4;p++){
      int nrow = (t>>4) + p*16;
      int kc = (t&15)*4;
      ushort4 o;
      o.x = f2bf(tile[kc+0][nrow]);
      o.y = f2bf(tile[kc+1][nrow]);
      o.z = f2bf(tile[kc+2][nrow]);
      o.w = f2bf(tile[kc+3][nrow]);
      *reinterpret_cast<ushort4*>(&out[(size_t)(n0+nrow)*K + k0 + kc]) = o;
    }
  }
}

// ---------------- bf16 MFMA GEMM: C = A[M][K] @ Bt[N][K]^T + bias ----------------
// Tile = (FM*32) x (FN*32), 4 waves in 2x2. 2-phase dbuf, issue-next-first.
// BK=64, 128B LDS rows, row&7 XOR swizzle.
// MODE 0: scatter Q*SC,K -> [b,h,t,d]; V -> [b,h,d,t] (fused transpose).
// MODE 1: fp32 out [M][N], swapped-operand D^T epilogue -> float4 stores.
template<int MODE, int FM, int FN>
__global__ __launch_bounds__(256) void k_gemm(
    const unsigned short* __restrict__ A,
    const unsigned short* __restrict__ Bt,
    const float* __restrict__ bias,
    void* __restrict__ Cout,
    int M, int N, int K)
{
  const int BK=64;
  const int TM=FM*32, TN=FN*32;
  const int ASZ=TM*BK, BSZ=TN*BK;
  __shared__ unsigned short As[2*ASZ];
  __shared__ unsigned short Bs[2*BSZ];
  int m0 = blockIdx.y*TM, n0 = blockIdx.x*TN;
  int t = threadIdx.x, lane = t&63, wid = t>>6;
  int wm = (wid>>1)*FM*16, wn = (wid&1)*FN*16;
  int g = lane>>4, r16 = lane&15;
  int rl  = lane>>3;                 // 0..7 = row&7
  int cle = (((lane&7) ^ rl) * 8);   // inverse-swizzled col (bf16 elems)
  int rsw = r16 & 7;                 // read-side row swizzle key
  f32x4 acc[FM][FN] = {};

  // prologue: stage tile 0 into buffer 0
  #pragma unroll
  for(int c=0;c<FM;c++){
    int rb = wid*FM*8 + c*8;
    gload_lds16(&A [(size_t)(m0+rb+rl)*K + cle], &As[rb*BK]);
  }
  #pragma unroll
  for(int c=0;c<FN;c++){
    int rb = wid*FN*8 + c*8;
    gload_lds16(&Bt[(size_t)(n0+rb+rl)*K + cle], &Bs[rb*BK]);
  }
  __syncthreads();

  const int NIT = K/BK;
  for(int it=0; it<NIT; ++it){
    int cur = it & 1;
    // issue next tile's loads FIRST -> in flight during compute (T3/T14)
    if(it+1 < NIT){
      int k0 = (it+1)*BK;
      #pragma unroll
      for(int c=0;c<FM;c++){
        int rb = wid*FM*8 + c*8;
        gload_lds16(&A [(size_t)(m0+rb+rl)*K + k0 + cle], &As[(cur^1)*ASZ + rb*BK]);
      }
      #pragma unroll
      for(int c=0;c<FN;c++){
        int rb = wid*FN*8 + c*8;
        gload_lds16(&Bt[(size_t)(n0+rb+rl)*K + k0 + cle], &Bs[(cur^1)*BSZ + rb*BK]);
      }
    }
    const unsigned short* Ab = &As[cur*ASZ];
    const unsigned short* Bb = &Bs[cur*BSZ];
    bf16x8 af[2][FM], bfr[2][FN];
    #pragma unroll
    for(int ks=0;ks<2;ks++){
      #pragma unroll
      for(int mi=0;mi<FM;mi++)
        af[ks][mi]  = *reinterpret_cast<const bf16x8*>(&Ab[(wm+mi*16+r16)*BK + (((ks*4+g)^rsw)*8)]);
      #pragma unroll
      for(int ni=0;ni<FN;ni++)
        bfr[ks][ni] = *reinterpret_cast<const bf16x8*>(&Bb[(wn+ni*16+r16)*BK + (((ks*4+g)^rsw)*8)]);
    }
    __builtin_amdgcn_s_setprio(1);
    #pragma unroll
    for(int ks=0;ks<2;ks++)
      #pragma unroll
      for(int mi=0;mi<FM;mi++)
        #pragma unroll
        for(int ni=0;ni<FN;ni++){
          if(MODE==0)
            acc[mi][ni] = __builtin_amdgcn_mfma_f32_16x16x32_bf16(af[ks][mi], bfr[ks][ni], acc[mi][ni], 0,0,0);
          else
            acc[mi][ni] = __builtin_amdgcn_mfma_f32_16x16x32_bf16(bfr[ks][ni], af[ks][mi], acc[mi][ni], 0,0,0);
        }
    __builtin_amdgcn_s_setprio(0);
    __syncthreads();   // drains next-tile gloads (had full compute phase in flight)
  }

  if(MODE==0){
    int which = (n0+wn)>>10;
    int h = ((n0+wn)&1023)>>6;
    int bb = m0>>11;
    int tt0 = (m0&2047) + wm;
    unsigned short* base = (unsigned short*)Cout;
    if(which < 2){
      // Q pre-scaled by (1/8)*log2(e) so attn uses sacc directly in exp2 domain
      float scale = (which==0) ? 0.18033688f : 1.0f;   // wave-uniform
      unsigned short* dst = base + (size_t)which*BT*N_EMBD
                          + (((size_t)bb*N_HEADv + h)*Tv + tt0)*HEADv;
      #pragma unroll
      for(int ni=0;ni<FN;ni++){
        float bv = bias[n0+wn+ni*16+r16];
        int d = ni*16 + r16;
        #pragma unroll
        for(int mi=0;mi<FM;mi++)
          #pragma unroll
          for(int reg=0;reg<4;reg++){
            int tt = mi*16 + g*4 + reg;
            dst[(size_t)tt*HEADv + d] = f2bf((acc[mi][ni][reg] + bv)*scale);
          }
      }
    } else {
      unsigned short* dst = base + 2ll*BT*N_EMBD
                          + (((size_t)bb*N_HEADv + h)*HEADv)*Tv + tt0;
      #pragma unroll
      for(int ni=0;ni<FN;ni++){
        float bv = bias[n0+wn+ni*16+r16];
        int d = ni*16 + r16;
        #pragma unroll
        for(int mi=0;mi<FM;mi++)
          #pragma unroll
          for(int reg=0;reg<4;reg++){
            int tt = mi*16 + g*4 + reg;
            dst[(size_t)d*Tv + tt] = f2bf(acc[mi][ni][reg] + bv);
          }
      }
    }
  } else {
    float* out = (float*)Cout;
    #pragma unroll
    for(int mi=0;mi<FM;mi++){
      int m = m0+wm+mi*16+r16;
      #pragma unroll
      for(int ni=0;ni<FN;ni++){
        int n = n0+wn+ni*16+g*4;
        float4 b4 = *reinterpret_cast<const float4*>(&bias[n]);
        float4 o4;
        o4.x = acc[mi][ni][0] + b4.x;
        o4.y = acc[mi][ni][1] + b4.y;
        o4.z = acc[mi][ni][2] + b4.z;
        o4.w = acc[mi][ni][3] + b4.w;
        *reinterpret_cast<float4*>(&out[(size_t)m*N + n]) = o4;
      }
    }
  }
}

// ---------------- flash attention (causal), split-K chunks ----------------
// Q pre-scaled by (1/8)log2e -> sacc is directly in exp2 domain.
// Iteration order: QK^T FIRST (critical ds_reads not queued behind staging
// ds_writes -- LDS ops drain in order per wave), THEN staging writes + next
// load issues (latency covered by softmax VALU), then softmax, Ps/PV, barrier.
__global__ __launch_bounds__(256) void k_attn(
    const unsigned short* __restrict__ QKV,
    unsigned short* __restrict__ O,
    unsigned short* __restrict__ partO,
    float2* __restrict__ stats)
{
  __shared__ unsigned short Ks[2][64][64];   // [buf][key][d], swizzled cols
  __shared__ unsigned short Vs[2][64][64];   // [buf][d][key]
  __shared__ unsigned short Ps[4][16][64];   // [wave][q][key]
  int blk = blockIdx.x;
  int bh = blk & 31;
  int j  = blk >> 5;
  int qt, kt0, ktN; bool single;
  if(j < 16)      { qt = 16+j;  kt0 = 0;  ktN = 16;    single = false; }
  else if(j < 32) { qt = 47-j;  kt0 = 16; ktN = qt+1;  single = false; }
  else            { qt = 47-j;  kt0 = 0;  ktN = qt+1;  single = true;  }

  int t = threadIdx.x, lane=t&63, wid=t>>6;
  int g = lane>>4, r16 = lane&15;
  const unsigned short* Qp  = QKV + (size_t)bh*Tv*HEADv;
  const unsigned short* Kp  = QKV + (size_t)BT*N_EMBD + (size_t)bh*Tv*HEADv;
  const unsigned short* Vtp = QKV + 2ll*BT*N_EMBD + (size_t)bh*HEADv*Tv;
  int q0 = qt*64 + wid*16;

  bf16x8 aq[2];   // B-operand: col = q = r16
  #pragma unroll
  for(int kb=0;kb<2;kb++)
    aq[kb] = *reinterpret_cast<const bf16x8*>(&Qp[(size_t)(q0+r16)*HEADv + kb*32 + g*8]);

  const short ONE = (short)0x3F80;           // bf16 1.0
  const bf16x8 ones8 = {ONE,ONE,ONE,ONE,ONE,ONE,ONE,ONE};

  f32x4 oacc[4] = {};
  f32x4 lacc = {};            // l via ones-MFMA (element 0 used)
  float m2 = 6.0f;            // warm init (log2 domain)

  // staging: thread covers rows t>>3 and t>>3+32, 16B slot t&7
  int r0 = t>>3, c0 = (t&7)*8;
  int r1 = r0 + 32;
  int sw0 = c0 ^ ((r0&7)<<3);
  int sw1 = c0 ^ ((r1&7)<<3);
  int rsw = (r16&7)<<3;

  // prologue: tile kt0 -> regs -> buf0 ; issue tile kt0+1 loads
  int4 kc0, kc1, vc0, vc1;
  kc0 = *reinterpret_cast<const int4*>(&Kp [(size_t)(kt0*64+r0)*HEADv + c0]);
  kc1 = *reinterpret_cast<const int4*>(&Kp [(size_t)(kt0*64+r1)*HEADv + c0]);
  vc0 = *reinterpret_cast<const int4*>(&Vtp[(size_t)r0*Tv + kt0*64 + c0]);
  vc1 = *reinterpret_cast<const int4*>(&Vtp[(size_t)r1*Tv + kt0*64 + c0]);
  *reinterpret_cast<int4*>(&Ks[0][r0][sw0]) = kc0;
  *reinterpret_cast<int4*>(&Ks[0][r1][sw1]) = kc1;
  *reinterpret_cast<int4*>(&Vs[0][r0][sw0]) = vc0;
  *reinterpret_cast<int4*>(&Vs[0][r1][sw1]) = vc1;
  if(ktN - kt0 > 1){
    kc0 = *reinterpret_cast<const int4*>(&Kp [(size_t)((kt0+1)*64+r0)*HEADv + c0]);
    kc1 = *reinterpret_cast<const int4*>(&Kp [(size_t)((kt0+1)*64+r1)*HEADv + c0]);
    vc0 = *reinterpret_cast<const int4*>(&Vtp[(size_t)r0*Tv + (kt0+1)*64 + c0]);
    vc1 = *reinterpret_cast<const int4*>(&Vtp[(size_t)r1*Tv + (kt0+1)*64 + c0]);
  }
  __syncthreads();

  for(int kt=kt0; kt<ktN; ++kt){
    int cur = kt & 1;

    // 1) S^T FIRST (already exp2-domain): critical ds_reads issue immediately
    f32x4 sacc[4];
    __builtin_amdgcn_s_setprio(1);
    #pragma unroll
    for(int nb=0;nb<4;nb++){
      sacc[nb] = (f32x4){0.f,0.f,0.f,0.f};
      #pragma unroll
      for(int kb=0;kb<2;kb++){
        bf16x8 bk = *reinterpret_cast<const bf16x8*>(&Ks[cur][nb*16+r16][(kb*32+g*8) ^ rsw]);
        sacc[nb] = __builtin_amdgcn_mfma_f32_16x16x32_bf16(bk, aq[kb], sacc[nb],0,0,0);
      }
    }
    __builtin_amdgcn_s_setprio(0);

    // 2) stage next tile (writes to buf cur^1: its prior readers passed the
    //    last barrier) + issue kt+2 loads; completion covered by softmax VALU
    if(kt+1 < ktN){
      *reinterpret_cast<int4*>(&Ks[cur^1][r0][sw0]) = kc0;
      *reinterpret_cast<int4*>(&Ks[cur^1][r1][sw1]) = kc1;
      *reinterpret_cast<int4*>(&Vs[cur^1][r0][sw0]) = vc0;
      *reinterpret_cast<int4*>(&Vs[cur^1][r1][sw1]) = vc1;
      if(kt+2 < ktN){
        kc0 = *reinterpret_cast<const int4*>(&Kp [(size_t)((kt+2)*64+r0)*HEADv + c0]);
        kc1 = *reinterpret_cast<const int4*>(&Kp [(size_t)((kt+2)*64+r1)*HEADv + c0]);
        vc0 = *reinterpret_cast<const int4*>(&Vtp[(size_t)r0*Tv + (kt+2)*64 + c0]);
        vc1 = *reinterpret_cast<const int4*>(&Vtp[(size_t)r1*Tv + (kt+2)*64 + c0]);
      }
    }

    // 3) softmax: mask (diag only) + speculative exp2 (no max-tree dep)
    bool diag = (kt == qt);
    float pv[4][4];
    if(diag){
      #pragma unroll
      for(int nb=0;nb<4;nb++)
        #pragma unroll
        for(int reg=0;reg<4;reg++){
          int keyin = nb*16 + g*4 + reg;
          if(keyin > wid*16 + r16) sacc[nb][reg] = -1e30f;
        }
    }
    #pragma unroll
    for(int nb=0;nb<4;nb++)
      #pragma unroll
      for(int reg=0;reg<4;reg++)
        pv[nb][reg] = __builtin_amdgcn_exp2f(sacc[nb][reg] - m2);

    // parallel path: row max -> rare repair branch
    float mxnb[4];
    #pragma unroll
    for(int nb=0;nb<4;nb++)
      mxnb[nb] = fmaxf(fmaxf(sacc[nb][0],sacc[nb][1]), fmaxf(sacc[nb][2],sacc[nb][3]));
    float mx = fmaxf(fmaxf(mxnb[0],mxnb[1]), fmaxf(mxnb[2],mxnb[3]));
    mx = fmaxf(mx, __shfl_xor(mx, 16, 64));
    mx = fmaxf(mx, __shfl_xor(mx, 32, 64));

    if(!__all(mx - m2 <= 11.5f)){
      float mn = fmaxf(m2, mx);
      float alpha = __builtin_amdgcn_exp2f(m2 - mn);
      lacc[0]*=alpha; lacc[1]*=alpha; lacc[2]*=alpha; lacc[3]*=alpha;
      #pragma unroll
      for(int nb=0;nb<4;nb++)
        #pragma unroll
        for(int reg=0;reg<4;reg++) oacc[nb][reg] *= alpha;
      m2 = mn;
      #pragma unroll
      for(int nb=0;nb<4;nb++)
        #pragma unroll
        for(int reg=0;reg<4;reg++)
          pv[nb][reg] = __builtin_amdgcn_exp2f(sacc[nb][reg] - m2);
    }

    // 4) P -> LDS (wave-private)
    #pragma unroll
    for(int nb=0;nb<4;nb++){
      union { uint32_t u[2]; int2 v; } w;
      w.u[0] = f2bf_fast(pv[nb][0]) | (f2bf_fast(pv[nb][1])<<16);
      w.u[1] = f2bf_fast(pv[nb][2]) | (f2bf_fast(pv[nb][3])<<16);
      *reinterpret_cast<int2*>(&Ps[wid][r16][(nb*16+g*4) ^ rsw]) = w.v;
    }

    // 5) PV (+ l via ones-MFMA)
    __builtin_amdgcn_s_setprio(1);
    #pragma unroll
    for(int kb=0;kb<2;kb++){
      bf16x8 ap = *reinterpret_cast<const bf16x8*>(&Ps[wid][r16][(kb*32+g*8) ^ rsw]);
      lacc = __builtin_amdgcn_mfma_f32_16x16x32_bf16(ones8, ap, lacc,0,0,0);
      #pragma unroll
      for(int nb=0;nb<4;nb++){
        bf16x8 bv = *reinterpret_cast<const bf16x8*>(&Vs[cur][nb*16+r16][(kb*32+g*8) ^ rsw]);
        oacc[nb] = __builtin_amdgcn_mfma_f32_16x16x32_bf16(bv, ap, oacc[nb],0,0,0);
      }
    }
    __builtin_amdgcn_s_setprio(0);
    __syncthreads();
  }

  float l = lacc[0];
  float rinv = 1.0f / l;
  if(single){
    int b = bh >> 4, h = bh & 15;
    size_t row = (size_t)b*Tv + q0 + r16;
    #pragma unroll
    for(int nb=0;nb<4;nb++){
      ushort4 o;
      o.x = f2bf(oacc[nb][0]*rinv);
      o.y = f2bf(oacc[nb][1]*rinv);
      o.z = f2bf(oacc[nb][2]*rinv);
      o.w = f2bf(oacc[nb][3]*rinv);
      *reinterpret_cast<ushort4*>(&O[row*N_EMBD + h*HEADv + nb*16 + g*4]) = o;
    }
  } else {
    int part = j*32 + bh;
    unsigned short* po = partO + (size_t)part*4096;
    int qloc = wid*16 + r16;
    #pragma unroll
    for(int nb=0;nb<4;nb++){
      ushort4 o;
      o.x = f2bf(oacc[nb][0]*rinv);
      o.y = f2bf(oacc[nb][1]*rinv);
      o.z = f2bf(oacc[nb][2]*rinv);
      o.w = f2bf(oacc[nb][3]*rinv);
      *reinterpret_cast<ushort4*>(&po[qloc*64 + nb*16 + g*4]) = o;
    }
    if(g==0) stats[part*64 + qloc] = make_float2(m2, l);
  }
}

// ---------------- merge two partials per (bh, qt>=16) ----------------
__global__ __launch_bounds__(256) void k_merge(
    const unsigned short* __restrict__ partO,
    const float2* __restrict__ stats,
    unsigned short* __restrict__ O)
{
  int blk = blockIdx.x;            // 512
  int bh = blk & 31, qt = 16 + (blk >> 5);
  int p0 = (qt-16)*32 + bh;
  int p1 = (47-qt)*32 + bh;
  int t = threadIdx.x;
  int q = t >> 2, d0 = (t&3)*16;
  float2 s0 = stats[p0*64 + q];
  float2 s1 = stats[p1*64 + q];
  float m = fmaxf(s0.x, s1.x);
  float w0 = s0.y * __builtin_amdgcn_exp2f(s0.x - m);
  float w1 = s1.y * __builtin_amdgcn_exp2f(s1.x - m);
  float rinv = 1.f/(w0+w1);
  w0 *= rinv; w1 *= rinv;
  const unsigned short* a = partO + (size_t)p0*4096 + q*64 + d0;
  const unsigned short* b = partO + (size_t)p1*4096 + q*64 + d0;
  int bb = bh >> 4, h = bh & 15;
  unsigned short* o = O + ((size_t)bb*Tv + qt*64 + q)*N_EMBD + h*HEADv + d0;
  #pragma unroll
  for(int half=0; half<2; ++half){
    union { int4 v; unsigned short s[8]; } ua, ub, uo;
    ua.v = *reinterpret_cast<const int4*>(a + half*8);
    ub.v = *reinterpret_cast<const int4*>(b + half*8);
    #pragma unroll
    for(int e=0;e<8;e++)
      uo.s[e] = f2bf(bf2f(ua.s[e])*w0 + bf2f(ub.s[e])*w1);
    *reinterpret_cast<int4*>(o + half*8) = uo.v;
  }
}

extern "C" void kernel_launch(void* const* d_in, const int* in_sizes, int n_in,
                              void* d_out, int out_size, void* d_ws, size_t ws_size,
                              hipStream_t stream){
  const float* x      = (const float*)d_in[0];
  const float* w_attn = (const float*)d_in[1];
  const float* b_attn = (const float*)d_in[2];
  const float* w_proj = (const float*)d_in[3];
  const float* b_proj = (const float*)d_in[4];
  char* ws = (char*)d_ws;
  unsigned short* xb  = (unsigned short*)ws;                        // 8 MB  (dead after gemm0 -> partO)
  unsigned short* qkv = (unsigned short*)(ws + 8ll*1024*1024);      // 24 MB (V third stored transposed)
  unsigned short* ob  = (unsigned short*)(ws + 32ll*1024*1024);     // 8 MB
  unsigned short* wat = (unsigned short*)(ws + 40ll*1024*1024);     // 6 MB  (dead after gemm0 -> stats)
  unsigned short* wpt = (unsigned short*)(ws + 46ll*1024*1024);     // 2 MB
  unsigned short* partO = xb;                                       // 1024 * 8KB = 8 MB
  float2*        stats  = (float2*)wat;                             // 1024 * 512B = 512 KB

  k_prep<<<dim3(3072),256,0,stream>>>(x, xb, w_attn, wat, w_proj, wpt);
  k_gemm<0,2,4><<<dim3(C3/128, BT/64),256,0,stream>>>(xb, wat, b_attn, (void*)qkv, BT, C3, N_EMBD);
  k_attn<<<dim3(48*32),256,0,stream>>>(qkv, ob, partO, stats);
  k_merge<<<dim3(512),256,0,stream>>>(partO, stats, ob);
  k_gemm<1,2,2><<<dim3(N_EMBD/64, BT/64),256,0,stream>>>(ob, wpt, b_proj, d_out, BT, N_EMBD, N_EMBD);
}

// Round 15
// 106.669 us; speedup vs baseline: 1.2795x; 1.0248x over previous
//
#include <hip/hip_runtime.h>
#include <stdint.h>

#define N_EMBD 1024
#define N_HEADv 16
#define HEADv 64
#define Bv 2
#define Tv 2048
#define BT (Bv*Tv)      // 4096
#define C3 (3*N_EMBD)   // 3072

typedef __attribute__((ext_vector_type(8))) short bf16x8;
typedef __attribute__((ext_vector_type(4))) float f32x4;

typedef __attribute__((address_space(3))) uint32_t lds_u32;
typedef const __attribute__((address_space(1))) uint32_t glb_u32;

__device__ __forceinline__ void gload_lds16(const void* g, void* l){
  __builtin_amdgcn_global_load_lds((glb_u32*)g, (lds_u32*)l, 16, 0, 0);
}

__device__ __forceinline__ unsigned short f2bf(float f){
  union { float f; uint32_t u; } v; v.f = f;
  uint32_t u = v.u;
  uint32_t r = u + 0x7FFFu + ((u>>16)&1u);
  return (unsigned short)(r>>16);
}
__device__ __forceinline__ float bf2f(unsigned short s){
  union { uint32_t u; float f; } v; v.u = ((uint32_t)s)<<16; return v.f;
}
// pack 2 f32 -> 2 bf16 (RNE) in ONE instruction (no builtin on gfx950; m240)
__device__ __forceinline__ uint32_t cvt_pk_bf16(float lo, float hi){
  uint32_t r;
  asm("v_cvt_pk_bf16_f32 %0, %1, %2" : "=v"(r) : "v"(lo), "v"(hi));
  return r;
}

// ---------------- fused prep: x->bf16 cvt + both weight transposes ----------------
__global__ __launch_bounds__(256) void k_prep(
    const float* __restrict__ x, unsigned short* __restrict__ xb,
    const float* __restrict__ w_attn, unsigned short* __restrict__ wat,
    const float* __restrict__ w_proj, unsigned short* __restrict__ wpt)
{
  __shared__ float tile[64][65];
  int blk = blockIdx.x;
  int t = threadIdx.x;
  if(blk < 2048){
    long i = ((long)blk*256 + t)*8;
    float4 a = *reinterpret_cast<const float4*>(x+i);
    float4 b = *reinterpret_cast<const float4*>(x+i+4);
    union { int4 v; unsigned short s[8]; } o;
    o.s[0]=f2bf(a.x); o.s[1]=f2bf(a.y); o.s[2]=f2bf(a.z); o.s[3]=f2bf(a.w);
    o.s[4]=f2bf(b.x); o.s[5]=f2bf(b.y); o.s[6]=f2bf(b.z); o.s[7]=f2bf(b.w);
    *reinterpret_cast<int4*>(xb+i) = o.v;
  } else {
    const float* in; unsigned short* out; int K, N, n0, k0;
    if(blk < 2816){
      int b = blk - 2048;
      in = w_attn; out = wat; K = N_EMBD; N = C3;
      n0 = (b % 48)*64; k0 = (b / 48)*64;
    } else {
      int b = blk - 2816;
      in = w_proj; out = wpt; K = N_EMBD; N = N_EMBD;
      n0 = (b % 16)*64; k0 = (b / 16)*64;
    }
    #pragma unroll
    for(int p=0;p<4;p++){
      int row = (t>>4) + p*16;
      int col4 = (t&15)*4;
      float4 v = *reinterpret_cast<const float4*>(&in[(size_t)(k0+row)*N + n0 + col4]);
      tile[row][col4+0]=v.x; tile[row][col4+1]=v.y; tile[row][col4+2]=v.z; tile[row][col4+3]=v.w;
    }
    __syncthreads();
    #pragma unroll
    for(int p=0;p<4;p++){
      int nrow = (t>>4) + p*16;
      int kc = (t&15)*4;
      ushort4 o;
      o.x = f2bf(tile[kc+0][nrow]);
      o.y = f2bf(tile[kc+1][nrow]);
      o.z = f2bf(tile[kc+2][nrow]);
      o.w = f2bf(tile[kc+3][nrow]);
      *reinterpret_cast<ushort4*>(&out[(size_t)(n0+nrow)*K + k0 + kc]) = o;
    }
  }
}

// ---------------- bf16 MFMA GEMM: C = A[M][K] @ Bt[N][K]^T + bias ----------------
// Tile = (FM*32) x (FN*32), 4 waves in 2x2. 2-phase dbuf, issue-next-first.
// BK=64, 128B LDS rows, row&7 XOR swizzle.
// MODE 0: scatter Q*SC,K -> [b,h,t,d]; V -> [b,h,d,t] (fused transpose).
// MODE 1: fp32 out [M][N], swapped-operand D^T epilogue -> float4 stores.
template<int MODE, int FM, int FN>
__global__ __launch_bounds__(256) void k_gemm(
    const unsigned short* __restrict__ A,
    const unsigned short* __restrict__ Bt,
    const float* __restrict__ bias,
    void* __restrict__ Cout,
    int M, int N, int K)
{
  const int BK=64;
  const int TM=FM*32, TN=FN*32;
  const int ASZ=TM*BK, BSZ=TN*BK;
  __shared__ unsigned short As[2*ASZ];
  __shared__ unsigned short Bs[2*BSZ];
  int m0 = blockIdx.y*TM, n0 = blockIdx.x*TN;
  int t = threadIdx.x, lane = t&63, wid = t>>6;
  int wm = (wid>>1)*FM*16, wn = (wid&1)*FN*16;
  int g = lane>>4, r16 = lane&15;
  int rl  = lane>>3;                 // 0..7 = row&7
  int cle = (((lane&7) ^ rl) * 8);   // inverse-swizzled col (bf16 elems)
  int rsw = r16 & 7;                 // read-side row swizzle key
  f32x4 acc[FM][FN] = {};

  // prologue: stage tile 0 into buffer 0
  #pragma unroll
  for(int c=0;c<FM;c++){
    int rb = wid*FM*8 + c*8;
    gload_lds16(&A [(size_t)(m0+rb+rl)*K + cle], &As[rb*BK]);
  }
  #pragma unroll
  for(int c=0;c<FN;c++){
    int rb = wid*FN*8 + c*8;
    gload_lds16(&Bt[(size_t)(n0+rb+rl)*K + cle], &Bs[rb*BK]);
  }
  __syncthreads();

  const int NIT = K/BK;
  for(int it=0; it<NIT; ++it){
    int cur = it & 1;
    // issue next tile's loads FIRST -> in flight during compute (T3/T14)
    if(it+1 < NIT){
      int k0 = (it+1)*BK;
      #pragma unroll
      for(int c=0;c<FM;c++){
        int rb = wid*FM*8 + c*8;
        gload_lds16(&A [(size_t)(m0+rb+rl)*K + k0 + cle], &As[(cur^1)*ASZ + rb*BK]);
      }
      #pragma unroll
      for(int c=0;c<FN;c++){
        int rb = wid*FN*8 + c*8;
        gload_lds16(&Bt[(size_t)(n0+rb+rl)*K + k0 + cle], &Bs[(cur^1)*BSZ + rb*BK]);
      }
    }
    const unsigned short* Ab = &As[cur*ASZ];
    const unsigned short* Bb = &Bs[cur*BSZ];
    bf16x8 af[2][FM], bfr[2][FN];
    #pragma unroll
    for(int ks=0;ks<2;ks++){
      #pragma unroll
      for(int mi=0;mi<FM;mi++)
        af[ks][mi]  = *reinterpret_cast<const bf16x8*>(&Ab[(wm+mi*16+r16)*BK + (((ks*4+g)^rsw)*8)]);
      #pragma unroll
      for(int ni=0;ni<FN;ni++)
        bfr[ks][ni] = *reinterpret_cast<const bf16x8*>(&Bb[(wn+ni*16+r16)*BK + (((ks*4+g)^rsw)*8)]);
    }
    __builtin_amdgcn_s_setprio(1);
    #pragma unroll
    for(int ks=0;ks<2;ks++)
      #pragma unroll
      for(int mi=0;mi<FM;mi++)
        #pragma unroll
        for(int ni=0;ni<FN;ni++){
          if(MODE==0)
            acc[mi][ni] = __builtin_amdgcn_mfma_f32_16x16x32_bf16(af[ks][mi], bfr[ks][ni], acc[mi][ni], 0,0,0);
          else
            acc[mi][ni] = __builtin_amdgcn_mfma_f32_16x16x32_bf16(bfr[ks][ni], af[ks][mi], acc[mi][ni], 0,0,0);
        }
    __builtin_amdgcn_s_setprio(0);
    __syncthreads();   // drains next-tile gloads (had full compute phase in flight)
  }

  if(MODE==0){
    int which = (n0+wn)>>10;
    int h = ((n0+wn)&1023)>>6;
    int bb = m0>>11;
    int tt0 = (m0&2047) + wm;
    unsigned short* base = (unsigned short*)Cout;
    if(which < 2){
      // Q pre-scaled by (1/8)*log2(e) so attn uses sacc directly in exp2 domain
      float scale = (which==0) ? 0.18033688f : 1.0f;   // wave-uniform
      unsigned short* dst = base + (size_t)which*BT*N_EMBD
                          + (((size_t)bb*N_HEADv + h)*Tv + tt0)*HEADv;
      #pragma unroll
      for(int ni=0;ni<FN;ni++){
        float bv = bias[n0+wn+ni*16+r16];
        int d = ni*16 + r16;
        #pragma unroll
        for(int mi=0;mi<FM;mi++)
          #pragma unroll
          for(int reg=0;reg<4;reg++){
            int tt = mi*16 + g*4 + reg;
            dst[(size_t)tt*HEADv + d] = f2bf((acc[mi][ni][reg] + bv)*scale);
          }
      }
    } else {
      unsigned short* dst = base + 2ll*BT*N_EMBD
                          + (((size_t)bb*N_HEADv + h)*HEADv)*Tv + tt0;
      #pragma unroll
      for(int ni=0;ni<FN;ni++){
        float bv = bias[n0+wn+ni*16+r16];
        int d = ni*16 + r16;
        #pragma unroll
        for(int mi=0;mi<FM;mi++)
          #pragma unroll
          for(int reg=0;reg<4;reg++){
            int tt = mi*16 + g*4 + reg;
            dst[(size_t)d*Tv + tt] = f2bf(acc[mi][ni][reg] + bv);
          }
      }
    }
  } else {
    float* out = (float*)Cout;
    #pragma unroll
    for(int mi=0;mi<FM;mi++){
      int m = m0+wm+mi*16+r16;
      #pragma unroll
      for(int ni=0;ni<FN;ni++){
        int n = n0+wn+ni*16+g*4;
        float4 b4 = *reinterpret_cast<const float4*>(&bias[n]);
        float4 o4;
        o4.x = acc[mi][ni][0] + b4.x;
        o4.y = acc[mi][ni][1] + b4.y;
        o4.z = acc[mi][ni][2] + b4.z;
        o4.w = acc[mi][ni][3] + b4.w;
        *reinterpret_cast<float4*>(&out[(size_t)m*N + n]) = o4;
      }
    }
  }
}

// ---------------- flash attention (causal), split-K chunks ----------------
// Q pre-scaled by (1/8)log2e -> sacc is directly in exp2 domain.
// VALU-lean softmax: speculative exp2 (no max dep); per-lane max3 tree feeds
// the __all vote directly (cross-lane row-reduce only inside the rare repair
// branch); P packed via v_cvt_pk_bf16_f32 (8 instrs vs 40 bit-twiddle ops);
// l via ones-MFMA.
__global__ __launch_bounds__(256) void k_attn(
    const unsigned short* __restrict__ QKV,
    unsigned short* __restrict__ O,
    unsigned short* __restrict__ partO,
    float2* __restrict__ stats)
{
  __shared__ unsigned short Ks[2][64][64];   // [buf][key][d], swizzled cols
  __shared__ unsigned short Vs[2][64][64];   // [buf][d][key]
  __shared__ unsigned short Ps[4][16][64];   // [wave][q][key]
  int blk = blockIdx.x;
  int bh = blk & 31;
  int j  = blk >> 5;
  int qt, kt0, ktN; bool single;
  if(j < 16)      { qt = 16+j;  kt0 = 0;  ktN = 16;    single = false; }
  else if(j < 32) { qt = 47-j;  kt0 = 16; ktN = qt+1;  single = false; }
  else            { qt = 47-j;  kt0 = 0;  ktN = qt+1;  single = true;  }

  int t = threadIdx.x, lane=t&63, wid=t>>6;
  int g = lane>>4, r16 = lane&15;
  const unsigned short* Qp  = QKV + (size_t)bh*Tv*HEADv;
  const unsigned short* Kp  = QKV + (size_t)BT*N_EMBD + (size_t)bh*Tv*HEADv;
  const unsigned short* Vtp = QKV + 2ll*BT*N_EMBD + (size_t)bh*HEADv*Tv;
  int q0 = qt*64 + wid*16;

  bf16x8 aq[2];   // B-operand: col = q = r16
  #pragma unroll
  for(int kb=0;kb<2;kb++)
    aq[kb] = *reinterpret_cast<const bf16x8*>(&Qp[(size_t)(q0+r16)*HEADv + kb*32 + g*8]);

  const short ONE = (short)0x3F80;           // bf16 1.0
  const bf16x8 ones8 = {ONE,ONE,ONE,ONE,ONE,ONE,ONE,ONE};

  f32x4 oacc[4] = {};
  f32x4 lacc = {};            // l via ones-MFMA (element 0 used)
  float m2 = 6.0f;            // warm init (log2 domain)

  // staging: thread covers rows t>>3 and t>>3+32, 16B slot t&7
  int r0 = t>>3, c0 = (t&7)*8;
  int r1 = r0 + 32;
  int sw0 = c0 ^ ((r0&7)<<3);
  int sw1 = c0 ^ ((r1&7)<<3);
  int rsw = (r16&7)<<3;

  // prologue: tile kt0 -> regs -> buf0 ; issue tile kt0+1 loads
  int4 kc0, kc1, vc0, vc1;
  kc0 = *reinterpret_cast<const int4*>(&Kp [(size_t)(kt0*64+r0)*HEADv + c0]);
  kc1 = *reinterpret_cast<const int4*>(&Kp [(size_t)(kt0*64+r1)*HEADv + c0]);
  vc0 = *reinterpret_cast<const int4*>(&Vtp[(size_t)r0*Tv + kt0*64 + c0]);
  vc1 = *reinterpret_cast<const int4*>(&Vtp[(size_t)r1*Tv + kt0*64 + c0]);
  *reinterpret_cast<int4*>(&Ks[0][r0][sw0]) = kc0;
  *reinterpret_cast<int4*>(&Ks[0][r1][sw1]) = kc1;
  *reinterpret_cast<int4*>(&Vs[0][r0][sw0]) = vc0;
  *reinterpret_cast<int4*>(&Vs[0][r1][sw1]) = vc1;
  if(ktN - kt0 > 1){
    kc0 = *reinterpret_cast<const int4*>(&Kp [(size_t)((kt0+1)*64+r0)*HEADv + c0]);
    kc1 = *reinterpret_cast<const int4*>(&Kp [(size_t)((kt0+1)*64+r1)*HEADv + c0]);
    vc0 = *reinterpret_cast<const int4*>(&Vtp[(size_t)r0*Tv + (kt0+1)*64 + c0]);
    vc1 = *reinterpret_cast<const int4*>(&Vtp[(size_t)r1*Tv + (kt0+1)*64 + c0]);
  }
  __syncthreads();

  for(int kt=kt0; kt<ktN; ++kt){
    int cur = kt & 1;

    // 1) S^T FIRST (already exp2-domain): critical ds_reads issue immediately
    f32x4 sacc[4];
    __builtin_amdgcn_s_setprio(1);
    #pragma unroll
    for(int nb=0;nb<4;nb++){
      sacc[nb] = (f32x4){0.f,0.f,0.f,0.f};
      #pragma unroll
      for(int kb=0;kb<2;kb++){
        bf16x8 bk = *reinterpret_cast<const bf16x8*>(&Ks[cur][nb*16+r16][(kb*32+g*8) ^ rsw]);
        sacc[nb] = __builtin_amdgcn_mfma_f32_16x16x32_bf16(bk, aq[kb], sacc[nb],0,0,0);
      }
    }
    __builtin_amdgcn_s_setprio(0);

    // 2) stage next tile (buf cur^1: prior readers passed the last barrier)
    //    + issue kt+2 loads; completion covered by softmax VALU
    if(kt+1 < ktN){
      *reinterpret_cast<int4*>(&Ks[cur^1][r0][sw0]) = kc0;
      *reinterpret_cast<int4*>(&Ks[cur^1][r1][sw1]) = kc1;
      *reinterpret_cast<int4*>(&Vs[cur^1][r0][sw0]) = vc0;
      *reinterpret_cast<int4*>(&Vs[cur^1][r1][sw1]) = vc1;
      if(kt+2 < ktN){
        kc0 = *reinterpret_cast<const int4*>(&Kp [(size_t)((kt+2)*64+r0)*HEADv + c0]);
        kc1 = *reinterpret_cast<const int4*>(&Kp [(size_t)((kt+2)*64+r1)*HEADv + c0]);
        vc0 = *reinterpret_cast<const int4*>(&Vtp[(size_t)r0*Tv + (kt+2)*64 + c0]);
        vc1 = *reinterpret_cast<const int4*>(&Vtp[(size_t)r1*Tv + (kt+2)*64 + c0]);
      }
    }

    // 3) softmax: mask (diag only) + speculative exp2 (no max-tree dep)
    bool diag = (kt == qt);
    float pv[4][4];
    if(diag){
      #pragma unroll
      for(int nb=0;nb<4;nb++)
        #pragma unroll
        for(int reg=0;reg<4;reg++){
          int keyin = nb*16 + g*4 + reg;
          if(keyin > wid*16 + r16) sacc[nb][reg] = -1e30f;
        }
    }
    #pragma unroll
    for(int nb=0;nb<4;nb++)
      #pragma unroll
      for(int reg=0;reg<4;reg++)
        pv[nb][reg] = __builtin_amdgcn_exp2f(sacc[nb][reg] - m2);

    // per-lane max via balanced triples (v_max3); vote needs no cross-lane
    // reduce: __all fires iff ANY lane's local max exceeds.
    float a0 = fmaxf(fmaxf(sacc[0][0],sacc[0][1]),sacc[0][2]);
    float a1 = fmaxf(fmaxf(sacc[0][3],sacc[1][0]),sacc[1][1]);
    float a2 = fmaxf(fmaxf(sacc[1][2],sacc[1][3]),sacc[2][0]);
    float a3 = fmaxf(fmaxf(sacc[2][1],sacc[2][2]),sacc[2][3]);
    float a4 = fmaxf(fmaxf(sacc[3][0],sacc[3][1]),sacc[3][2]);
    float b0 = fmaxf(fmaxf(a0,a1),a2);
    float b1 = fmaxf(fmaxf(a3,a4),sacc[3][3]);
    float mx = fmaxf(b0,b1);

    if(!__all(mx - m2 <= 11.5f)){
      // rare repair: full per-row (cross-g) reduce so row-lanes agree on m2
      mx = fmaxf(mx, __shfl_xor(mx, 16, 64));
      mx = fmaxf(mx, __shfl_xor(mx, 32, 64));
      float mn = fmaxf(m2, mx);
      float alpha = __builtin_amdgcn_exp2f(m2 - mn);
      lacc[0]*=alpha; lacc[1]*=alpha; lacc[2]*=alpha; lacc[3]*=alpha;
      #pragma unroll
      for(int nb=0;nb<4;nb++)
        #pragma unroll
        for(int reg=0;reg<4;reg++) oacc[nb][reg] *= alpha;
      m2 = mn;
      #pragma unroll
      for(int nb=0;nb<4;nb++)
        #pragma unroll
        for(int reg=0;reg<4;reg++)
          pv[nb][reg] = __builtin_amdgcn_exp2f(sacc[nb][reg] - m2);
    }

    // 4) P -> LDS (wave-private), packed via v_cvt_pk_bf16_f32
    #pragma unroll
    for(int nb=0;nb<4;nb++){
      int2 w;
      w.x = (int)cvt_pk_bf16(pv[nb][0], pv[nb][1]);
      w.y = (int)cvt_pk_bf16(pv[nb][2], pv[nb][3]);
      *reinterpret_cast<int2*>(&Ps[wid][r16][(nb*16+g*4) ^ rsw]) = w;
    }

    // 5) PV (+ l via ones-MFMA)
    __builtin_amdgcn_s_setprio(1);
    #pragma unroll
    for(int kb=0;kb<2;kb++){
      bf16x8 ap = *reinterpret_cast<const bf16x8*>(&Ps[wid][r16][(kb*32+g*8) ^ rsw]);
      lacc = __builtin_amdgcn_mfma_f32_16x16x32_bf16(ones8, ap, lacc,0,0,0);
      #pragma unroll
      for(int nb=0;nb<4;nb++){
        bf16x8 bv = *reinterpret_cast<const bf16x8*>(&Vs[cur][nb*16+r16][(kb*32+g*8) ^ rsw]);
        oacc[nb] = __builtin_amdgcn_mfma_f32_16x16x32_bf16(bv, ap, oacc[nb],0,0,0);
      }
    }
    __builtin_amdgcn_s_setprio(0);
    __syncthreads();
  }

  float l = lacc[0];
  float rinv = 1.0f / l;
  if(single){
    int b = bh >> 4, h = bh & 15;
    size_t row = (size_t)b*Tv + q0 + r16;
    #pragma unroll
    for(int nb=0;nb<4;nb++){
      ushort4 o;
      o.x = f2bf(oacc[nb][0]*rinv);
      o.y = f2bf(oacc[nb][1]*rinv);
      o.z = f2bf(oacc[nb][2]*rinv);
      o.w = f2bf(oacc[nb][3]*rinv);
      *reinterpret_cast<ushort4*>(&O[row*N_EMBD + h*HEADv + nb*16 + g*4]) = o;
    }
  } else {
    int part = j*32 + bh;
    unsigned short* po = partO + (size_t)part*4096;
    int qloc = wid*16 + r16;
    #pragma unroll
    for(int nb=0;nb<4;nb++){
      ushort4 o;
      o.x = f2bf(oacc[nb][0]*rinv);
      o.y = f2bf(oacc[nb][1]*rinv);
      o.z = f2bf(oacc[nb][2]*rinv);
      o.w = f2bf(oacc[nb][3]*rinv);
      *reinterpret_cast<ushort4*>(&po[qloc*64 + nb*16 + g*4]) = o;
    }
    if(g==0) stats[part*64 + qloc] = make_float2(m2, l);
  }
}

// ---------------- merge two partials per (bh, qt>=16) ----------------
__global__ __launch_bounds__(256) void k_merge(
    const unsigned short* __restrict__ partO,
    const float2* __restrict__ stats,
    unsigned short* __restrict__ O)
{
  int blk = blockIdx.x;            // 512
  int bh = blk & 31, qt = 16 + (blk >> 5);
  int p0 = (qt-16)*32 + bh;
  int p1 = (47-qt)*32 + bh;
  int t = threadIdx.x;
  int q = t >> 2, d0 = (t&3)*16;
  float2 s0 = stats[p0*64 + q];
  float2 s1 = stats[p1*64 + q];
  float m = fmaxf(s0.x, s1.x);
  float w0 = s0.y * __builtin_amdgcn_exp2f(s0.x - m);
  float w1 = s1.y * __builtin_amdgcn_exp2f(s1.x - m);
  float rinv = 1.f/(w0+w1);
  w0 *= rinv; w1 *= rinv;
  const unsigned short* a = partO + (size_t)p0*4096 + q*64 + d0;
  const unsigned short* b = partO + (size_t)p1*4096 + q*64 + d0;
  int bb = bh >> 4, h = bh & 15;
  unsigned short* o = O + ((size_t)bb*Tv + qt*64 + q)*N_EMBD + h*HEADv + d0;
  #pragma unroll
  for(int half=0; half<2; ++half){
    union { int4 v; unsigned short s[8]; } ua, ub, uo;
    ua.v = *reinterpret_cast<const int4*>(a + half*8);
    ub.v = *reinterpret_cast<const int4*>(b + half*8);
    #pragma unroll
    for(int e=0;e<8;e++)
      uo.s[e] = f2bf(bf2f(ua.s[e])*w0 + bf2f(ub.s[e])*w1);
    *reinterpret_cast<int4*>(o + half*8) = uo.v;
  }
}

extern "C" void kernel_launch(void* const* d_in, const int* in_sizes, int n_in,
                              void* d_out, int out_size, void* d_ws, size_t ws_size,
                              hipStream_t stream){
  const float* x      = (const float*)d_in[0];
  const float* w_attn = (const float*)d_in[1];
  const float* b_attn = (const float*)d_in[2];
  const float* w_proj = (const float*)d_in[3];
  const float* b_proj = (const float*)d_in[4];
  char* ws = (char*)d_ws;
  unsigned short* xb  = (unsigned short*)ws;                        // 8 MB  (dead after gemm0 -> partO)
  unsigned short* qkv = (unsigned short*)(ws + 8ll*1024*1024);      // 24 MB (V third stored transposed)
  unsigned short* ob  = (unsigned short*)(ws + 32ll*1024*1024);     // 8 MB
  unsigned short* wat = (unsigned short*)(ws + 40ll*1024*1024);     // 6 MB  (dead after gemm0 -> stats)
  unsigned short* wpt = (unsigned short*)(ws + 46ll*1024*1024);     // 2 MB
  unsigned short* partO = xb;                                       // 1024 * 8KB = 8 MB
  float2*        stats  = (float2*)wat;                             // 1024 * 512B = 512 KB

  k_prep<<<dim3(3072),256,0,stream>>>(x, xb, w_attn, wat, w_proj, wpt);
  k_gemm<0,2,4><<<dim3(C3/128, BT/64),256,0,stream>>>(xb, wat, b_attn, (void*)qkv, BT, C3, N_EMBD);
  k_attn<<<dim3(48*32),256,0,stream>>>(qkv, ob, partO, stats);
  k_merge<<<dim3(512),256,0,stream>>>(partO, stats, ob);
  k_gemm<1,2,2><<<dim3(N_EMBD/64, BT/64),256,0,stream>>>(ob, wpt, b_proj, d_out, BT, N_EMBD, N_EMBD);
}